// Round 7
// baseline (169.507 us; speedup 1.0000x reference)
//
#include <hip/hip_runtime.h>

// ---------------------------------------------------------------------------
// Channel_Seq_Big_Attention: B=8,N=128,M=8,D=512,H=8,DH=64, INNER=512
// Softmax is over axis=2 of (b,h,i,j,m,z) == QUERY seq axis i.
// Pipeline (fp16 compute, fp32 accumulate):
//   1. w_q,w_kv -> wqkvT f16 [n(1536)][k(512)]; w_out -> woutT [4096][4096]
//   2. QKV GEMM (8192x512)@(512x1536): A reg-staged from x f32 (fused
//      convert, swizzled LDS), B via global_load_lds. Scatter:
//        Qb [bh][m][i][d] (scaled by log2e/8 -> softmax uses exp2 directly),
//        Kb [bh][z][j][d], VbT [bh][d][m*128+j]
//   3. attention (ROUND-5 VERBATIM, known-pass): block=(bh,z), 512 threads,
//      bh=blk&63 (XCD-local). 3-barrier m-loop, single lds_v, padded lds_p.
//   4. final GEMM (1024x4096)@(4096x4096), split-K=4 (grid 1024),
//      fp16 partials -> k_reduce4 adds partials + bias -> y (f32)
// ---------------------------------------------------------------------------

typedef _Float16 h16;
typedef _Float16 h16x4 __attribute__((ext_vector_type(4)));
typedef _Float16 h16x8 __attribute__((ext_vector_type(8)));
typedef float f32x4 __attribute__((ext_vector_type(4)));

#define MFMA16(a, b, c) __builtin_amdgcn_mfma_f32_16x16x32_f16(a, b, c, 0, 0, 0)

// async global->LDS, 16B per lane; lds dest must be wave-uniform base
__device__ __forceinline__ void gload16(const h16* g, h16* l) {
  __builtin_amdgcn_global_load_lds(
      (const __attribute__((address_space(1))) void*)g,
      (__attribute__((address_space(3))) void*)l, 16, 0, 0);
}

// ---------------- prep kernels ----------------

// dst[c][r] = (h16) src[r][c];  R,C multiples of 64. block (64,4)
__global__ __launch_bounds__(256) void k_transpose(const float* __restrict__ src,
                                                   h16* __restrict__ dst, int R, int C) {
  __shared__ h16 tile[64][72];
  int tx = threadIdx.x, ty = threadIdx.y;
  int r0 = blockIdx.y * 64, c0 = blockIdx.x * 64;
#pragma unroll
  for (int s = 0; s < 16; ++s) {
    int r = ty + s * 4;
    tile[r][tx] = (h16)src[(size_t)(r0 + r) * C + c0 + tx];
  }
  __syncthreads();
#pragma unroll
  for (int s = 0; s < 16; ++s) {
    int rr = ty + s * 4;
    dst[(size_t)(c0 + rr) * R + r0 + tx] = tile[tx][rr];
  }
}

// ---------------- QKV projection GEMM (fused x-convert) ----------------
// A = x (8192x512 f32, converted in staging), Bt = wqkvT (1536 x 512 f16).
__global__ __launch_bounds__(256, 3) void k_qkv_gemm(const float* __restrict__ X,
                                                     const h16* __restrict__ Bt,
                                                     h16* __restrict__ Qb,
                                                     h16* __restrict__ Kb,
                                                     h16* __restrict__ VbT) {
  __shared__ __align__(16) h16 As[128 * 64];
  __shared__ __align__(16) h16 Bs[128 * 64];
  int tid = threadIdx.x;
  int tileM = blockIdx.x / 12, tileN = blockIdx.x % 12;
  int w = tid >> 6, l = tid & 63, g = l >> 4, t = l & 15;
  int wr = w >> 1, wc = w & 1;
  int lr = l >> 3, lc = (l & 7) * 8;
  int ar = tid >> 1, ac0 = (tid & 1) * 32;  // A-stage: row, col0 (f32)
  const float* Xbase = X + (size_t)(tileM * 128 + ar) * 512 + ac0;
  const h16* Bbase = Bt + (size_t)(tileN * 128) * 512;
  f32x4 acc[4][4];
#pragma unroll
  for (int i = 0; i < 4; ++i)
#pragma unroll
    for (int j = 0; j < 4; ++j) acc[i][j] = (f32x4){0.f, 0.f, 0.f, 0.f};

  for (int k0 = 0; k0 < 512; k0 += 64) {
    // B: async DMA (linear LDS)
#pragma unroll
    for (int c = 0; c < 4; ++c) {
      int chunk = w * 4 + c, row0 = chunk * 8;
      gload16(Bbase + (size_t)(row0 + lr) * 512 + k0 + lc, &Bs[chunk * 512]);
    }
    // A: reg-stage f32 -> cvt f16 -> swizzled ds_write (granule G ^= row&7)
    float4 xa[8];
#pragma unroll
    for (int s = 0; s < 8; ++s) xa[s] = *(const float4*)(Xbase + k0 + s * 4);
#pragma unroll
    for (int c = 0; c < 4; ++c) {
      h16x8 v8;
      v8[0] = (h16)xa[2 * c].x;     v8[1] = (h16)xa[2 * c].y;
      v8[2] = (h16)xa[2 * c].z;     v8[3] = (h16)xa[2 * c].w;
      v8[4] = (h16)xa[2 * c + 1].x; v8[5] = (h16)xa[2 * c + 1].y;
      v8[6] = (h16)xa[2 * c + 1].z; v8[7] = (h16)xa[2 * c + 1].w;
      int G = (4 * (tid & 1) + c) ^ (ar & 7);
      *(h16x8*)&As[ar * 64 + G * 8] = v8;
    }
    __syncthreads();
#pragma unroll
    for (int kk = 0; kk < 64; kk += 32) {
      h16x8 af[4], bfr[4];
#pragma unroll
      for (int mi = 0; mi < 4; ++mi) {
        int rr = wr * 64 + mi * 16 + t;
        int G = ((kk >> 3) + g) ^ (rr & 7);
        af[mi] = *(const h16x8*)&As[rr * 64 + G * 8];
      }
#pragma unroll
      for (int ni = 0; ni < 4; ++ni) bfr[ni] = *(const h16x8*)&Bs[(wc * 64 + ni * 16 + t) * 64 + kk + g * 8];
#pragma unroll
      for (int mi = 0; mi < 4; ++mi)
#pragma unroll
        for (int ni = 0; ni < 4; ++ni) acc[mi][ni] = MFMA16(af[mi], bfr[ni], acc[mi][ni]);
    }
    __syncthreads();
  }
  // scatter epilogue: C<512 -> Q (scaled by log2e/8), C<1024 -> K, else -> V^T
#pragma unroll
  for (int mi = 0; mi < 4; ++mi) {
#pragma unroll
    for (int ni = 0; ni < 4; ++ni) {
      int C = tileN * 128 + wc * 64 + ni * 16 + t;
#pragma unroll
      for (int r = 0; r < 4; ++r) {
        int R = tileM * 128 + wr * 64 + mi * 16 + 4 * g + r;
        float val = acc[mi][ni][r];
        int b = R >> 10, rm = R & 1023;
        int i = rm >> 3, m = rm & 7;
        int bh8 = b * 8;
        if (C < 512) {
          int h = C >> 6, d = C & 63;
          Qb[((size_t)(bh8 + h) * 8 + m) * 8192 + i * 64 + d] = (h16)(val * 0.18033688f);
        } else if (C < 1024) {
          int c2 = C - 512, h = c2 >> 6, d = c2 & 63;
          Kb[((size_t)(bh8 + h) * 1024 + (m * 128 + i)) * 64 + d] = (h16)val;
        } else {
          int c2 = C - 1024, h = c2 >> 6, d = c2 & 63;
          VbT[((size_t)(bh8 + h) * 64 + d) * 1024 + (m * 128 + i)] = (h16)val;
        }
      }
    }
  }
}

// ---------------- attention (ROUND-5 VERBATIM, known-pass) ----------------
// grid 512; bh = blk&63 (same bh -> same XCD-L2), z = blk>>6.
// 512 threads = 8 waves -> 16 waves/CU at 2 blocks/CU.
// Wave w: QK^T j-rows [w*16,w*16+16); PV i-rows [w*16,w*16+16), all 64 d.
// Q_m/V_m DMA-staged into LDS with XOR swizzle (chunk ^= row&7) applied on
// the per-lane GLOBAL source address (LDS dest stays linear, m173 pattern).
__global__ __launch_bounds__(512, 4) void k_attn(const h16* __restrict__ Qbuf,
                                                 const h16* __restrict__ Kbuf,
                                                 const h16* __restrict__ VbT,
                                                 h16* __restrict__ Ob) {
  __shared__ __align__(16) h16 lds_q[128 * 64];   // Q_m [i][dh], swizzled, 16KB
  __shared__ __align__(16) h16 lds_v[64 * 128];   // V_m [d][j], swizzled, 16KB
  __shared__ __align__(16) h16 lds_p[128][136];   // P^T [i][j], padded, 34.8KB
  int blk = blockIdx.x;
  int bh = blk & 63, z = blk >> 6;
  int b = bh >> 3, h = bh & 7;
  const h16* Qb = Qbuf + (size_t)bh * 65536;              // [m][i][d]
  const h16* Kz = Kbuf + (size_t)bh * 65536 + z * 8192;   // [j][d]
  const h16* Vb = VbT + (size_t)bh * 65536;               // [d][u=m*128+j]
  int tid = threadIdx.x, w = tid >> 6, l = tid & 63, g = l >> 4, t = l & 15;

  // staging lane maps (swizzle on global source; LDS dest linear)
  int qs_r0 = l >> 3, qs_ch = l & 7;    // Q: 8 rows/KB, chunk of 8 h16
  int vs_r0 = l >> 4, vs_ch = l & 15;   // V: 4 rows/KB, chunk of 8 h16

  // K fragments in registers, loaded ONCE (z-fixed; wave w owns 16 j-rows)
  h16x8 kf[2];
#pragma unroll
  for (int kk = 0; kk < 2; ++kk)
    kf[kk] = *(const h16x8*)&Kz[(w * 16 + t) * 64 + kk * 32 + g * 8];

  f32x4 oa[4];
#pragma unroll
  for (int dt = 0; dt < 4; ++dt) oa[dt] = (f32x4){0.f, 0.f, 0.f, 0.f};

  // prologue: stage Q_0 and V_0
  {
    const h16* Qm = Qb;
#pragma unroll
    for (int s = 0; s < 2; ++s) {
      int r = w * 16 + s * 8 + qs_r0;
      gload16(Qm + r * 64 + ((qs_ch ^ (r & 7)) << 3), &lds_q[(w * 16 + s * 8) * 64]);
    }
#pragma unroll
    for (int s = 0; s < 2; ++s) {
      int r = w * 8 + s * 4 + vs_r0;
      gload16(Vb + (size_t)r * 1024 + ((vs_ch ^ (r & 7)) << 3), &lds_v[(w * 8 + s * 4) * 128]);
    }
  }

  for (int m = 0; m < 8; ++m) {
    __syncthreads();  // staged Q_m/V_m visible (barrier drains DMA vmcnt)

    // T = K_z @ Q_m^T : wave w -> j-rows [w*16,+16) x 128 i-cols
    f32x4 accS[8];
#pragma unroll
    for (int nt = 0; nt < 8; ++nt) accS[nt] = (f32x4){0.f, 0.f, 0.f, 0.f};
#pragma unroll
    for (int kk = 0; kk < 2; ++kk)
#pragma unroll
      for (int nt = 0; nt < 8; ++nt) {
        int rr = nt * 16 + t, c = kk * 4 + g;
        h16x8 bq = *(const h16x8*)&lds_q[rr * 64 + ((c ^ (rr & 7)) << 3)];
        accS[nt] = MFMA16(kf[kk], bq, accS[nt]);
      }

    // softmax over i (cols): in-reg over nt + 16 t-lanes via shfl; no max-sub
    float inv[4];
#pragma unroll
    for (int r = 0; r < 4; ++r) {
      float sum = 0.f;
#pragma unroll
      for (int nt = 0; nt < 8; ++nt) {
        float p = exp2f(accS[nt][r]);
        accS[nt][r] = p;
        sum += p;
      }
#pragma unroll
      for (int msk = 1; msk < 16; msk <<= 1) sum += __shfl_xor(sum, msk);
      inv[r] = 1.f / sum;
    }
    // normalize + cvt + P^T write: lds_p[i = nt*16+t][j = w*16+4g+r]
#pragma unroll
    for (int nt = 0; nt < 8; ++nt) {
      h16x4 pk;
#pragma unroll
      for (int r = 0; r < 4; ++r) pk[r] = (h16)(accS[nt][r] * inv[r]);
      *(h16x4*)&lds_p[nt * 16 + t][w * 16 + 4 * g] = pk;
    }
    __syncthreads();  // lds_p ready; lds_q free

    // overlap: stage Q_{m+1} into lds_q while PV computes
    if (m < 7) {
      const h16* Qm = Qb + (m + 1) * 8192;
#pragma unroll
      for (int s = 0; s < 2; ++s) {
        int r = w * 16 + s * 8 + qs_r0;
        gload16(Qm + r * 64 + ((qs_ch ^ (r & 7)) << 3), &lds_q[(w * 16 + s * 8) * 64]);
      }
    }

    // PV: out[i][d] += sum_j P^T[j][i] * V_m[j][d]; wave w -> i-rows [w*16,+16)
#pragma unroll
    for (int kk = 0; kk < 4; ++kk) {
      h16x8 ap = *(const h16x8*)&lds_p[w * 16 + t][kk * 32 + g * 8];
#pragma unroll
      for (int dt = 0; dt < 4; ++dt) {
        int rr = dt * 16 + t, c = kk * 4 + g;
        h16x8 vf = *(const h16x8*)&lds_v[rr * 128 + ((c ^ (rr & 7)) << 3)];
        oa[dt] = MFMA16(ap, vf, oa[dt]);
      }
    }
    __syncthreads();  // all PV reads of lds_v/lds_p done

    if (m < 7) {
      const h16* Vm = Vb + (m + 1) * 128;
#pragma unroll
      for (int s = 0; s < 2; ++s) {
        int r = w * 8 + s * 4 + vs_r0;
        gload16(Vm + (size_t)r * 1024 + ((vs_ch ^ (r & 7)) << 3), &lds_v[(w * 8 + s * 4) * 128]);
      }
    }
  }

  // store out_z: Ob[b*128 + i][z*512 + h*64 + d]
#pragma unroll
  for (int dt = 0; dt < 4; ++dt)
#pragma unroll
    for (int r = 0; r < 4; ++r) {
      int i = w * 16 + 4 * g + r;
      Ob[(size_t)(b * 128 + i) * 4096 + z * 512 + h * 64 + dt * 16 + t] = (h16)oa[dt][r];
    }
}

// ---------------- final projection GEMM, split-K=4 ----------------
// A = Ob (1024x4096), Bt = woutT (4096 x 4096). Grid 1024 = 4 kslices x 256
// tiles -> 4 blocks/CU. Each block: K=1024 (16 K-steps). fp16 partials.
__global__ __launch_bounds__(256, 4) void k_final_gemm(const h16* __restrict__ A,
                                                       const h16* __restrict__ Bt,
                                                       h16* __restrict__ P) {
  __shared__ __align__(16) h16 As[128 * 64];
  __shared__ __align__(16) h16 Bs[128 * 64];
  int tid = threadIdx.x;
  int ks = blockIdx.x >> 8, tile = blockIdx.x & 255;
  int tileM = tile >> 5, tileN = tile & 31;
  int w = tid >> 6, l = tid & 63, g = l >> 4, t = l & 15;
  int wr = w >> 1, wc = w & 1;
  int lr = l >> 3, lc = (l & 7) * 8;
  const h16* Abase = A + (size_t)(tileM * 128) * 4096 + ks * 1024;
  const h16* Bbase = Bt + (size_t)(tileN * 128) * 4096 + ks * 1024;
  f32x4 acc[4][4];
#pragma unroll
  for (int i = 0; i < 4; ++i)
#pragma unroll
    for (int j = 0; j < 4; ++j) acc[i][j] = (f32x4){0.f, 0.f, 0.f, 0.f};

  for (int k0 = 0; k0 < 1024; k0 += 64) {
#pragma unroll
    for (int c = 0; c < 4; ++c) {
      int chunk = w * 4 + c, row0 = chunk * 8;
      gload16(Abase + (size_t)(row0 + lr) * 4096 + k0 + lc, &As[chunk * 512]);
      gload16(Bbase + (size_t)(row0 + lr) * 4096 + k0 + lc, &Bs[chunk * 512]);
    }
    __syncthreads();
#pragma unroll
    for (int kk = 0; kk < 64; kk += 32) {
      h16x8 af[4], bfr[4];
#pragma unroll
      for (int mi = 0; mi < 4; ++mi) af[mi] = *(const h16x8*)&As[(wr * 64 + mi * 16 + t) * 64 + kk + g * 8];
#pragma unroll
      for (int ni = 0; ni < 4; ++ni) bfr[ni] = *(const h16x8*)&Bs[(wc * 64 + ni * 16 + t) * 64 + kk + g * 8];
#pragma unroll
      for (int mi = 0; mi < 4; ++mi)
#pragma unroll
        for (int ni = 0; ni < 4; ++ni) acc[mi][ni] = MFMA16(af[mi], bfr[ni], acc[mi][ni]);
    }
    __syncthreads();
  }
  h16* Pk = P + (size_t)ks * 4194304;
#pragma unroll
  for (int mi = 0; mi < 4; ++mi) {
#pragma unroll
    for (int ni = 0; ni < 4; ++ni) {
      int C = tileN * 128 + wc * 64 + ni * 16 + t;
#pragma unroll
      for (int r = 0; r < 4; ++r) {
        int R = tileM * 128 + wr * 64 + mi * 16 + 4 * g + r;
        Pk[(size_t)R * 4096 + C] = (h16)acc[mi][ni][r];
      }
    }
  }
}

// y = p0+p1+p2+p3 + bias; 8 elems/thread, grid 2048
__global__ __launch_bounds__(256) void k_reduce4(const h16* __restrict__ P,
                                                 const float* __restrict__ bias,
                                                 float* __restrict__ Y) {
  int idx = blockIdx.x * 256 + threadIdx.x;
  size_t base = (size_t)idx * 8;
  h16x8 p0 = *(const h16x8*)&P[base];
  h16x8 p1 = *(const h16x8*)&P[base + 4194304];
  h16x8 p2 = *(const h16x8*)&P[base + 8388608];
  h16x8 p3 = *(const h16x8*)&P[base + 12582912];
  int cb = (int)(base & 4095);
  float4 b0 = *(const float4*)&bias[cb];
  float4 b1 = *(const float4*)&bias[cb + 4];
  float4 o0, o1;
  o0.x = (float)p0[0] + (float)p1[0] + (float)p2[0] + (float)p3[0] + b0.x;
  o0.y = (float)p0[1] + (float)p1[1] + (float)p2[1] + (float)p3[1] + b0.y;
  o0.z = (float)p0[2] + (float)p1[2] + (float)p2[2] + (float)p3[2] + b0.z;
  o0.w = (float)p0[3] + (float)p1[3] + (float)p2[3] + (float)p3[3] + b0.w;
  o1.x = (float)p0[4] + (float)p1[4] + (float)p2[4] + (float)p3[4] + b1.x;
  o1.y = (float)p0[5] + (float)p1[5] + (float)p2[5] + (float)p3[5] + b1.y;
  o1.z = (float)p0[6] + (float)p1[6] + (float)p2[6] + (float)p3[6] + b1.z;
  o1.w = (float)p0[7] + (float)p1[7] + (float)p2[7] + (float)p3[7] + b1.w;
  *(float4*)&Y[base] = o0;
  *(float4*)&Y[base + 4] = o1;
}

// ---------------- launch ----------------

extern "C" void kernel_launch(void* const* d_in, const int* in_sizes, int n_in,
                              void* d_out, int out_size, void* d_ws, size_t ws_size,
                              hipStream_t stream) {
  const float* x = (const float*)d_in[0];
  const float* w_q = (const float*)d_in[1];
  const float* w_kv = (const float*)d_in[2];
  const float* w_out = (const float*)d_in[3];
  const float* b_out = (const float*)d_in[4];
  float* y = (float*)d_out;

  char* ws = (char*)d_ws;
  h16* woutT = (h16*)(ws + 0);          // 32 MB  (alive to the end)
  h16* Ob    = (h16*)(ws + 33554432);   //  8 MB  (alive to the end)
  h16* wqkvT = (h16*)(ws + 50331648);   //  1.5MB (dead after qkv)
  h16* Qb    = (h16*)(ws + 51904512);   //  8 MB  (dead after attn)
  h16* Kb    = (h16*)(ws + 60293120);   //  8 MB  (dead after attn)
  h16* VbT   = (h16*)(ws + 68681728);   //  8 MB  (dead after attn)
  h16* Pp    = (h16*)(ws + 41943040);   // 32 MB partials, overlays dead region
  (void)ws_size; (void)in_sizes; (void)n_in; (void)out_size;

  k_transpose<<<dim3(8, 8), dim3(64, 4), 0, stream>>>(w_q, wqkvT, 512, 512);
  k_transpose<<<dim3(16, 8), dim3(64, 4), 0, stream>>>(w_kv, wqkvT + 512 * 512, 512, 1024);
  k_transpose<<<dim3(64, 64), dim3(64, 4), 0, stream>>>(w_out, woutT, 4096, 4096);
  k_qkv_gemm<<<dim3(768), dim3(256), 0, stream>>>(x, wqkvT, Qb, Kb, VbT);
  k_attn<<<dim3(512), dim3(512), 0, stream>>>(Qb, Kb, VbT, Ob);
  k_final_gemm<<<dim3(1024), dim3(256), 0, stream>>>(Ob, woutT, Pp);
  k_reduce4<<<dim3(2048), dim3(256), 0, stream>>>(Pp, b_out, y);
}

// Round 8
// 164.971 us; speedup vs baseline: 1.0275x; 1.0275x over previous
//
#include <hip/hip_runtime.h>

// ---------------------------------------------------------------------------
// Channel_Seq_Big_Attention: B=8,N=128,M=8,D=512,H=8,DH=64, INNER=512
// Softmax is over axis=2 of (b,h,i,j,m,z) == QUERY seq axis i.
// Pipeline (fp16 compute, fp32 accumulate):
//   1. w_q,w_kv -> wqkvT f16 [n(1536)][k(512)]; w_out -> woutT [4096][4096]
//   2. QKV GEMM (8192x512)@(512x1536): A reg-staged from x f32 (fused
//      convert, swizzled LDS), B via global_load_lds. XCD-chunked grid:
//      each XCD owns 8 tileM x all tileN (x-panel L2-resident). Scatter:
//        Qb [bh][m][i][d] (scaled by log2e/8), Kb [bh][z][j][d],
//        VbT [bh][d][m*128+j]
//   3. attention (round-5 structure, known-pass): block=(bh,z), 512 threads,
//      bh=blk&63 (XCD-local). 3-barrier m-loop, single lds_v, padded lds_p.
//   4. final GEMM (1024x4096)@(4096x4096), split-K=4, XCD-chunked grid
//      (4 tileN per XCD -> 4MB woutT slice L2-resident), fp16 partials
//      -> k_reduce4 adds partials + bias -> y (f32)
// ---------------------------------------------------------------------------

typedef _Float16 h16;
typedef _Float16 h16x4 __attribute__((ext_vector_type(4)));
typedef _Float16 h16x8 __attribute__((ext_vector_type(8)));
typedef float f32x4 __attribute__((ext_vector_type(4)));

#define MFMA16(a, b, c) __builtin_amdgcn_mfma_f32_16x16x32_f16(a, b, c, 0, 0, 0)

// async global->LDS, 16B per lane; lds dest must be wave-uniform base
__device__ __forceinline__ void gload16(const h16* g, h16* l) {
  __builtin_amdgcn_global_load_lds(
      (const __attribute__((address_space(1))) void*)g,
      (__attribute__((address_space(3))) void*)l, 16, 0, 0);
}

// ---------------- prep kernels ----------------

// dst[c][r] = (h16) src[r][c];  R,C multiples of 64. block (64,4)
__global__ __launch_bounds__(256) void k_transpose(const float* __restrict__ src,
                                                   h16* __restrict__ dst, int R, int C) {
  __shared__ h16 tile[64][72];
  int tx = threadIdx.x, ty = threadIdx.y;
  int r0 = blockIdx.y * 64, c0 = blockIdx.x * 64;
#pragma unroll
  for (int s = 0; s < 16; ++s) {
    int r = ty + s * 4;
    tile[r][tx] = (h16)src[(size_t)(r0 + r) * C + c0 + tx];
  }
  __syncthreads();
#pragma unroll
  for (int s = 0; s < 16; ++s) {
    int rr = ty + s * 4;
    dst[(size_t)(c0 + rr) * R + r0 + tx] = tile[tx][rr];
  }
}

// ---------------- QKV projection GEMM (fused x-convert, XCD-chunked) -------
// A = x (8192x512 f32, converted in staging), Bt = wqkvT (1536 x 512 f16).
__global__ __launch_bounds__(256, 3) void k_qkv_gemm(const float* __restrict__ X,
                                                     const h16* __restrict__ Bt,
                                                     h16* __restrict__ Qb,
                                                     h16* __restrict__ Kb,
                                                     h16* __restrict__ VbT) {
  __shared__ __align__(16) h16 As[128 * 64];
  __shared__ __align__(16) h16 Bs[128 * 64];
  int tid = threadIdx.x;
  // XCD-chunked mapping: 768 blocks, 8 XCDs, 96 logical tiles per XCD.
  // XCD k (= blk&7, dispatch round-robin) gets tileM in [k*8, k*8+8) x all 12
  // tileN -> per-XCD x working set 2MB f32 + B 1.5MB fits 4MB L2.
  int lg = (blockIdx.x & 7) * 96 + (blockIdx.x >> 3);
  int tileM = lg / 12, tileN = lg % 12;
  int w = tid >> 6, l = tid & 63, g = l >> 4, t = l & 15;
  int wr = w >> 1, wc = w & 1;
  int lr = l >> 3, lc = (l & 7) * 8;
  int ar = tid >> 1, ac0 = (tid & 1) * 32;  // A-stage: row, col0 (f32)
  const float* Xbase = X + (size_t)(tileM * 128 + ar) * 512 + ac0;
  const h16* Bbase = Bt + (size_t)(tileN * 128) * 512;
  f32x4 acc[4][4];
#pragma unroll
  for (int i = 0; i < 4; ++i)
#pragma unroll
    for (int j = 0; j < 4; ++j) acc[i][j] = (f32x4){0.f, 0.f, 0.f, 0.f};

  for (int k0 = 0; k0 < 512; k0 += 64) {
    // B: async DMA (linear LDS)
#pragma unroll
    for (int c = 0; c < 4; ++c) {
      int chunk = w * 4 + c, row0 = chunk * 8;
      gload16(Bbase + (size_t)(row0 + lr) * 512 + k0 + lc, &Bs[chunk * 512]);
    }
    // A: reg-stage f32 -> cvt f16 -> swizzled ds_write (granule G ^= row&7)
    float4 xa[8];
#pragma unroll
    for (int s = 0; s < 8; ++s) xa[s] = *(const float4*)(Xbase + k0 + s * 4);
#pragma unroll
    for (int c = 0; c < 4; ++c) {
      h16x8 v8;
      v8[0] = (h16)xa[2 * c].x;     v8[1] = (h16)xa[2 * c].y;
      v8[2] = (h16)xa[2 * c].z;     v8[3] = (h16)xa[2 * c].w;
      v8[4] = (h16)xa[2 * c + 1].x; v8[5] = (h16)xa[2 * c + 1].y;
      v8[6] = (h16)xa[2 * c + 1].z; v8[7] = (h16)xa[2 * c + 1].w;
      int G = (4 * (tid & 1) + c) ^ (ar & 7);
      *(h16x8*)&As[ar * 64 + G * 8] = v8;
    }
    __syncthreads();
#pragma unroll
    for (int kk = 0; kk < 64; kk += 32) {
      h16x8 af[4], bfr[4];
#pragma unroll
      for (int mi = 0; mi < 4; ++mi) {
        int rr = wr * 64 + mi * 16 + t;
        int G = ((kk >> 3) + g) ^ (rr & 7);
        af[mi] = *(const h16x8*)&As[rr * 64 + G * 8];
      }
#pragma unroll
      for (int ni = 0; ni < 4; ++ni) bfr[ni] = *(const h16x8*)&Bs[(wc * 64 + ni * 16 + t) * 64 + kk + g * 8];
#pragma unroll
      for (int mi = 0; mi < 4; ++mi)
#pragma unroll
        for (int ni = 0; ni < 4; ++ni) acc[mi][ni] = MFMA16(af[mi], bfr[ni], acc[mi][ni]);
    }
    __syncthreads();
  }
  // scatter epilogue: C<512 -> Q (scaled by log2e/8), C<1024 -> K, else -> V^T
#pragma unroll
  for (int mi = 0; mi < 4; ++mi) {
#pragma unroll
    for (int ni = 0; ni < 4; ++ni) {
      int C = tileN * 128 + wc * 64 + ni * 16 + t;
#pragma unroll
      for (int r = 0; r < 4; ++r) {
        int R = tileM * 128 + wr * 64 + mi * 16 + 4 * g + r;
        float val = acc[mi][ni][r];
        int b = R >> 10, rm = R & 1023;
        int i = rm >> 3, m = rm & 7;
        int bh8 = b * 8;
        if (C < 512) {
          int h = C >> 6, d = C & 63;
          Qb[((size_t)(bh8 + h) * 8 + m) * 8192 + i * 64 + d] = (h16)(val * 0.18033688f);
        } else if (C < 1024) {
          int c2 = C - 512, h = c2 >> 6, d = c2 & 63;
          Kb[((size_t)(bh8 + h) * 1024 + (m * 128 + i)) * 64 + d] = (h16)val;
        } else {
          int c2 = C - 1024, h = c2 >> 6, d = c2 & 63;
          VbT[((size_t)(bh8 + h) * 64 + d) * 1024 + (m * 128 + i)] = (h16)val;
        }
      }
    }
  }
}

// ---------------- attention (round-5 structure, known-pass) ----------------
// grid 512; bh = blk&63 (same bh -> same XCD-L2), z = blk>>6.
// 512 threads = 8 waves -> 16 waves/CU at 2 blocks/CU.
__global__ __launch_bounds__(512, 4) void k_attn(const h16* __restrict__ Qbuf,
                                                 const h16* __restrict__ Kbuf,
                                                 const h16* __restrict__ VbT,
                                                 h16* __restrict__ Ob) {
  __shared__ __align__(16) h16 lds_q[128 * 64];   // Q_m [i][dh], swizzled, 16KB
  __shared__ __align__(16) h16 lds_v[64 * 128];   // V_m [d][j], swizzled, 16KB
  __shared__ __align__(16) h16 lds_p[128][136];   // P^T [i][j], padded, 34.8KB
  int blk = blockIdx.x;
  int bh = blk & 63, z = blk >> 6;
  int b = bh >> 3, h = bh & 7;
  const h16* Qb = Qbuf + (size_t)bh * 65536;              // [m][i][d]
  const h16* Kz = Kbuf + (size_t)bh * 65536 + z * 8192;   // [j][d]
  const h16* Vb = VbT + (size_t)bh * 65536;               // [d][u=m*128+j]
  int tid = threadIdx.x, w = tid >> 6, l = tid & 63, g = l >> 4, t = l & 15;

  int qs_r0 = l >> 3, qs_ch = l & 7;    // Q: 8 rows/KB, chunk of 8 h16
  int vs_r0 = l >> 4, vs_ch = l & 15;   // V: 4 rows/KB, chunk of 8 h16

  // K fragments in registers, loaded ONCE (z-fixed; wave w owns 16 j-rows)
  h16x8 kf[2];
#pragma unroll
  for (int kk = 0; kk < 2; ++kk)
    kf[kk] = *(const h16x8*)&Kz[(w * 16 + t) * 64 + kk * 32 + g * 8];

  f32x4 oa[4];
#pragma unroll
  for (int dt = 0; dt < 4; ++dt) oa[dt] = (f32x4){0.f, 0.f, 0.f, 0.f};

  // prologue: stage Q_0 and V_0
  {
    const h16* Qm = Qb;
#pragma unroll
    for (int s = 0; s < 2; ++s) {
      int r = w * 16 + s * 8 + qs_r0;
      gload16(Qm + r * 64 + ((qs_ch ^ (r & 7)) << 3), &lds_q[(w * 16 + s * 8) * 64]);
    }
#pragma unroll
    for (int s = 0; s < 2; ++s) {
      int r = w * 8 + s * 4 + vs_r0;
      gload16(Vb + (size_t)r * 1024 + ((vs_ch ^ (r & 7)) << 3), &lds_v[(w * 8 + s * 4) * 128]);
    }
  }

  for (int m = 0; m < 8; ++m) {
    __syncthreads();  // staged Q_m/V_m visible (barrier drains DMA vmcnt)

    // T = K_z @ Q_m^T : wave w -> j-rows [w*16,+16) x 128 i-cols
    f32x4 accS[8];
#pragma unroll
    for (int nt = 0; nt < 8; ++nt) accS[nt] = (f32x4){0.f, 0.f, 0.f, 0.f};
#pragma unroll
    for (int kk = 0; kk < 2; ++kk)
#pragma unroll
      for (int nt = 0; nt < 8; ++nt) {
        int rr = nt * 16 + t, c = kk * 4 + g;
        h16x8 bq = *(const h16x8*)&lds_q[rr * 64 + ((c ^ (rr & 7)) << 3)];
        accS[nt] = MFMA16(kf[kk], bq, accS[nt]);
      }

    // softmax over i (cols): in-reg over nt + 16 t-lanes via shfl; no max-sub
    float inv[4];
#pragma unroll
    for (int r = 0; r < 4; ++r) {
      float sum = 0.f;
#pragma unroll
      for (int nt = 0; nt < 8; ++nt) {
        float p = exp2f(accS[nt][r]);
        accS[nt][r] = p;
        sum += p;
      }
#pragma unroll
      for (int msk = 1; msk < 16; msk <<= 1) sum += __shfl_xor(sum, msk);
      inv[r] = 1.f / sum;
    }
    // normalize + cvt + P^T write: lds_p[i = nt*16+t][j = w*16+4g+r]
#pragma unroll
    for (int nt = 0; nt < 8; ++nt) {
      h16x4 pk;
#pragma unroll
      for (int r = 0; r < 4; ++r) pk[r] = (h16)(accS[nt][r] * inv[r]);
      *(h16x4*)&lds_p[nt * 16 + t][w * 16 + 4 * g] = pk;
    }
    __syncthreads();  // lds_p ready; lds_q free

    // overlap: stage Q_{m+1} into lds_q while PV computes
    if (m < 7) {
      const h16* Qm = Qb + (m + 1) * 8192;
#pragma unroll
      for (int s = 0; s < 2; ++s) {
        int r = w * 16 + s * 8 + qs_r0;
        gload16(Qm + r * 64 + ((qs_ch ^ (r & 7)) << 3), &lds_q[(w * 16 + s * 8) * 64]);
      }
    }

    // PV: out[i][d] += sum_j P^T[j][i] * V_m[j][d]; wave w -> i-rows [w*16,+16)
#pragma unroll
    for (int kk = 0; kk < 4; ++kk) {
      h16x8 ap = *(const h16x8*)&lds_p[w * 16 + t][kk * 32 + g * 8];
#pragma unroll
      for (int dt = 0; dt < 4; ++dt) {
        int rr = dt * 16 + t, c = kk * 4 + g;
        h16x8 vf = *(const h16x8*)&lds_v[rr * 128 + ((c ^ (rr & 7)) << 3)];
        oa[dt] = MFMA16(ap, vf, oa[dt]);
      }
    }
    __syncthreads();  // all PV reads of lds_v/lds_p done

    if (m < 7) {
      const h16* Vm = Vb + (m + 1) * 128;
#pragma unroll
      for (int s = 0; s < 2; ++s) {
        int r = w * 8 + s * 4 + vs_r0;
        gload16(Vm + (size_t)r * 1024 + ((vs_ch ^ (r & 7)) << 3), &lds_v[(w * 8 + s * 4) * 128]);
      }
    }
  }

  // store out_z: Ob[b*128 + i][z*512 + h*64 + d]
#pragma unroll
  for (int dt = 0; dt < 4; ++dt)
#pragma unroll
    for (int r = 0; r < 4; ++r) {
      int i = w * 16 + 4 * g + r;
      Ob[(size_t)(b * 128 + i) * 4096 + z * 512 + h * 64 + dt * 16 + t] = (h16)oa[dt][r];
    }
}

// ---------------- final projection GEMM, split-K=4, XCD-chunked ----------
// A = Ob (1024x4096), Bt = woutT (4096 x 4096). Grid 1024 = 4 blocks/CU.
// XCD k gets tileN in [k*4, k*4+4) x all tileM x all ks -> per-XCD woutT
// slice = 4MB, L2-resident; A (8MB) shared via L3.
__global__ __launch_bounds__(256, 4) void k_final_gemm(const h16* __restrict__ A,
                                                       const h16* __restrict__ Bt,
                                                       h16* __restrict__ P) {
  __shared__ __align__(16) h16 As[128 * 64];
  __shared__ __align__(16) h16 Bs[128 * 64];
  int tid = threadIdx.x;
  int lg = (blockIdx.x & 7) * 128 + (blockIdx.x >> 3);
  int tileN = lg >> 5;        // [xcd*4, xcd*4+4)
  int rem = lg & 31;
  int tileM = rem >> 2, ks = rem & 3;
  int w = tid >> 6, l = tid & 63, g = l >> 4, t = l & 15;
  int wr = w >> 1, wc = w & 1;
  int lr = l >> 3, lc = (l & 7) * 8;
  const h16* Abase = A + (size_t)(tileM * 128) * 4096 + ks * 1024;
  const h16* Bbase = Bt + (size_t)(tileN * 128) * 4096 + ks * 1024;
  f32x4 acc[4][4];
#pragma unroll
  for (int i = 0; i < 4; ++i)
#pragma unroll
    for (int j = 0; j < 4; ++j) acc[i][j] = (f32x4){0.f, 0.f, 0.f, 0.f};

  for (int k0 = 0; k0 < 1024; k0 += 64) {
#pragma unroll
    for (int c = 0; c < 4; ++c) {
      int chunk = w * 4 + c, row0 = chunk * 8;
      gload16(Abase + (size_t)(row0 + lr) * 4096 + k0 + lc, &As[chunk * 512]);
      gload16(Bbase + (size_t)(row0 + lr) * 4096 + k0 + lc, &Bs[chunk * 512]);
    }
    __syncthreads();
#pragma unroll
    for (int kk = 0; kk < 64; kk += 32) {
      h16x8 af[4], bfr[4];
#pragma unroll
      for (int mi = 0; mi < 4; ++mi) af[mi] = *(const h16x8*)&As[(wr * 64 + mi * 16 + t) * 64 + kk + g * 8];
#pragma unroll
      for (int ni = 0; ni < 4; ++ni) bfr[ni] = *(const h16x8*)&Bs[(wc * 64 + ni * 16 + t) * 64 + kk + g * 8];
#pragma unroll
      for (int mi = 0; mi < 4; ++mi)
#pragma unroll
        for (int ni = 0; ni < 4; ++ni) acc[mi][ni] = MFMA16(af[mi], bfr[ni], acc[mi][ni]);
    }
    __syncthreads();
  }
  h16* Pk = P + (size_t)ks * 4194304;
#pragma unroll
  for (int mi = 0; mi < 4; ++mi) {
#pragma unroll
    for (int ni = 0; ni < 4; ++ni) {
      int C = tileN * 128 + wc * 64 + ni * 16 + t;
#pragma unroll
      for (int r = 0; r < 4; ++r) {
        int R = tileM * 128 + wr * 64 + mi * 16 + 4 * g + r;
        Pk[(size_t)R * 4096 + C] = (h16)acc[mi][ni][r];
      }
    }
  }
}

// y = p0+p1+p2+p3 + bias; 8 elems/thread, grid 2048
__global__ __launch_bounds__(256) void k_reduce4(const h16* __restrict__ P,
                                                 const float* __restrict__ bias,
                                                 float* __restrict__ Y) {
  int idx = blockIdx.x * 256 + threadIdx.x;
  size_t base = (size_t)idx * 8;
  h16x8 p0 = *(const h16x8*)&P[base];
  h16x8 p1 = *(const h16x8*)&P[base + 4194304];
  h16x8 p2 = *(const h16x8*)&P[base + 8388608];
  h16x8 p3 = *(const h16x8*)&P[base + 12582912];
  int cb = (int)(base & 4095);
  float4 b0 = *(const float4*)&bias[cb];
  float4 b1 = *(const float4*)&bias[cb + 4];
  float4 o0, o1;
  o0.x = (float)p0[0] + (float)p1[0] + (float)p2[0] + (float)p3[0] + b0.x;
  o0.y = (float)p0[1] + (float)p1[1] + (float)p2[1] + (float)p3[1] + b0.y;
  o0.z = (float)p0[2] + (float)p1[2] + (float)p2[2] + (float)p3[2] + b0.z;
  o0.w = (float)p0[3] + (float)p1[3] + (float)p2[3] + (float)p3[3] + b0.w;
  o1.x = (float)p0[4] + (float)p1[4] + (float)p2[4] + (float)p3[4] + b1.x;
  o1.y = (float)p0[5] + (float)p1[5] + (float)p2[5] + (float)p3[5] + b1.y;
  o1.z = (float)p0[6] + (float)p1[6] + (float)p2[6] + (float)p3[6] + b1.z;
  o1.w = (float)p0[7] + (float)p1[7] + (float)p2[7] + (float)p3[7] + b1.w;
  *(float4*)&Y[base] = o0;
  *(float4*)&Y[base + 4] = o1;
}

// ---------------- launch ----------------

extern "C" void kernel_launch(void* const* d_in, const int* in_sizes, int n_in,
                              void* d_out, int out_size, void* d_ws, size_t ws_size,
                              hipStream_t stream) {
  const float* x = (const float*)d_in[0];
  const float* w_q = (const float*)d_in[1];
  const float* w_kv = (const float*)d_in[2];
  const float* w_out = (const float*)d_in[3];
  const float* b_out = (const float*)d_in[4];
  float* y = (float*)d_out;

  char* ws = (char*)d_ws;
  h16* woutT = (h16*)(ws + 0);          // 32 MB  (alive to the end)
  h16* Ob    = (h16*)(ws + 33554432);   //  8 MB  (alive to the end)
  h16* wqkvT = (h16*)(ws + 50331648);   //  1.5MB (dead after qkv)
  h16* Qb    = (h16*)(ws + 51904512);   //  8 MB  (dead after attn)
  h16* Kb    = (h16*)(ws + 60293120);   //  8 MB  (dead after attn)
  h16* VbT   = (h16*)(ws + 68681728);   //  8 MB  (dead after attn)
  h16* Pp    = (h16*)(ws + 41943040);   // 32 MB partials, overlays dead region
  (void)ws_size; (void)in_sizes; (void)n_in; (void)out_size;

  k_transpose<<<dim3(8, 8), dim3(64, 4), 0, stream>>>(w_q, wqkvT, 512, 512);
  k_transpose<<<dim3(16, 8), dim3(64, 4), 0, stream>>>(w_kv, wqkvT + 512 * 512, 512, 1024);
  k_transpose<<<dim3(64, 64), dim3(64, 4), 0, stream>>>(w_out, woutT, 4096, 4096);
  k_qkv_gemm<<<dim3(768), dim3(256), 0, stream>>>(x, wqkvT, Qb, Kb, VbT);
  k_attn<<<dim3(512), dim3(512), 0, stream>>>(Qb, Kb, VbT, Ob);
  k_final_gemm<<<dim3(1024), dim3(256), 0, stream>>>(Ob, woutT, Pp);
  k_reduce4<<<dim3(2048), dim3(256), 0, stream>>>(Pp, b_out, y);
}

// Round 9
// 157.994 us; speedup vs baseline: 1.0729x; 1.0442x over previous
//
#include <hip/hip_runtime.h>

// ---------------------------------------------------------------------------
// Channel_Seq_Big_Attention: B=8,N=128,M=8,D=512,H=8,DH=64, INNER=512
// Softmax is over axis=2 of (b,h,i,j,m,z) == QUERY seq axis i.
// Pipeline (fp16 compute, fp32 accumulate):
//   1. x -> xh (f16); w_q,w_kv -> wqkvT f16 [n][k]; w_out -> woutT [4096][4096]
//   2. QKV GEMM (8192x512)@(512x1536): A,B both via global_load_lds (f16),
//      XCD-chunked grid (x-panel L2-resident per XCD). Scatter:
//        Qb [bh][m][i][d] (scaled by log2e/8), Kb [bh][z][j][d],
//        VbT [bh][d][m*128+j]
//   3. attention (round-5 structure): block=(bh,z), 512 threads, bh=blk&63
//      (XCD-local). 3-barrier m-loop, single lds_v, padded lds_p.
//   4. final GEMM (1024x4096)@(4096x4096), split-K=4, XCD-chunked grid,
//      fp16 partials -> k_reduce4 adds partials + bias -> y (f32)
// NOTE (lesson r7/r8): do NOT fuse f32->f16 conversion into GEMM staging —
// it displaces global_load_lds with a synchronous load+cvt+ds_write chain
// and costs ~25us of latency; separate convert + async DMA is faster.
// ---------------------------------------------------------------------------

typedef _Float16 h16;
typedef _Float16 h16x4 __attribute__((ext_vector_type(4)));
typedef _Float16 h16x8 __attribute__((ext_vector_type(8)));
typedef float f32x4 __attribute__((ext_vector_type(4)));

#define MFMA16(a, b, c) __builtin_amdgcn_mfma_f32_16x16x32_f16(a, b, c, 0, 0, 0)

// async global->LDS, 16B per lane; lds dest must be wave-uniform base
__device__ __forceinline__ void gload16(const h16* g, h16* l) {
  __builtin_amdgcn_global_load_lds(
      (const __attribute__((address_space(1))) void*)g,
      (__attribute__((address_space(3))) void*)l, 16, 0, 0);
}

// ---------------- prep kernels ----------------

__global__ __launch_bounds__(256) void k_convert_x(const float* __restrict__ src,
                                                   h16* __restrict__ dst) {
  int idx = blockIdx.x * 256 + threadIdx.x;  // 8 elements per thread
  const float4* s4 = (const float4*)src;
  float4 a = s4[idx * 2];
  float4 b = s4[idx * 2 + 1];
  h16x8 o;
  o[0] = (h16)a.x; o[1] = (h16)a.y; o[2] = (h16)a.z; o[3] = (h16)a.w;
  o[4] = (h16)b.x; o[5] = (h16)b.y; o[6] = (h16)b.z; o[7] = (h16)b.w;
  *(h16x8*)&dst[(size_t)idx * 8] = o;
}

// dst[c][r] = (h16) src[r][c];  R,C multiples of 64. block (64,4)
__global__ __launch_bounds__(256) void k_transpose(const float* __restrict__ src,
                                                   h16* __restrict__ dst, int R, int C) {
  __shared__ h16 tile[64][72];
  int tx = threadIdx.x, ty = threadIdx.y;
  int r0 = blockIdx.y * 64, c0 = blockIdx.x * 64;
#pragma unroll
  for (int s = 0; s < 16; ++s) {
    int r = ty + s * 4;
    tile[r][tx] = (h16)src[(size_t)(r0 + r) * C + c0 + tx];
  }
  __syncthreads();
#pragma unroll
  for (int s = 0; s < 16; ++s) {
    int rr = ty + s * 4;
    dst[(size_t)(c0 + rr) * R + r0 + tx] = tile[tx][rr];
  }
}

// ---------------- QKV projection GEMM (async staging, XCD-chunked) --------
// A = xh (8192x512 f16), Bt = wqkvT (1536 x 512 f16), scatter epilogue.
__global__ __launch_bounds__(256, 3) void k_qkv_gemm(const h16* __restrict__ A,
                                                     const h16* __restrict__ Bt,
                                                     h16* __restrict__ Qb,
                                                     h16* __restrict__ Kb,
                                                     h16* __restrict__ VbT) {
  __shared__ __align__(16) h16 As[128 * 64];
  __shared__ __align__(16) h16 Bs[128 * 64];
  int tid = threadIdx.x;
  // XCD-chunked: XCD k (= blk&7) owns tileM in [k*8,k*8+8) x all 12 tileN;
  // per-XCD working set = 1MB x-panel (f16) + 1.5MB B -> L2-resident.
  int lg = (blockIdx.x & 7) * 96 + (blockIdx.x >> 3);
  int tileM = lg / 12, tileN = lg % 12;
  int w = tid >> 6, l = tid & 63, g = l >> 4, t = l & 15;
  int wr = w >> 1, wc = w & 1;
  int lr = l >> 3, lc = (l & 7) * 8;  // staging: lane -> (row-in-chunk, k-col)
  const h16* Abase = A + (size_t)(tileM * 128) * 512;
  const h16* Bbase = Bt + (size_t)(tileN * 128) * 512;
  f32x4 acc[4][4];
#pragma unroll
  for (int i = 0; i < 4; ++i)
#pragma unroll
    for (int j = 0; j < 4; ++j) acc[i][j] = (f32x4){0.f, 0.f, 0.f, 0.f};

  for (int k0 = 0; k0 < 512; k0 += 64) {
#pragma unroll
    for (int c = 0; c < 4; ++c) {
      int chunk = w * 4 + c, row0 = chunk * 8;
      gload16(Abase + (size_t)(row0 + lr) * 512 + k0 + lc, &As[chunk * 512]);
      gload16(Bbase + (size_t)(row0 + lr) * 512 + k0 + lc, &Bs[chunk * 512]);
    }
    __syncthreads();
#pragma unroll
    for (int kk = 0; kk < 64; kk += 32) {
      h16x8 af[4], bfr[4];
#pragma unroll
      for (int mi = 0; mi < 4; ++mi) af[mi] = *(const h16x8*)&As[(wr * 64 + mi * 16 + t) * 64 + kk + g * 8];
#pragma unroll
      for (int ni = 0; ni < 4; ++ni) bfr[ni] = *(const h16x8*)&Bs[(wc * 64 + ni * 16 + t) * 64 + kk + g * 8];
#pragma unroll
      for (int mi = 0; mi < 4; ++mi)
#pragma unroll
        for (int ni = 0; ni < 4; ++ni) acc[mi][ni] = MFMA16(af[mi], bfr[ni], acc[mi][ni]);
    }
    __syncthreads();
  }
  // scatter epilogue: C<512 -> Q (scaled by log2e/8), C<1024 -> K, else -> V^T
#pragma unroll
  for (int mi = 0; mi < 4; ++mi) {
#pragma unroll
    for (int ni = 0; ni < 4; ++ni) {
      int C = tileN * 128 + wc * 64 + ni * 16 + t;
#pragma unroll
      for (int r = 0; r < 4; ++r) {
        int R = tileM * 128 + wr * 64 + mi * 16 + 4 * g + r;
        float val = acc[mi][ni][r];
        int b = R >> 10, rm = R & 1023;
        int i = rm >> 3, m = rm & 7;
        int bh8 = b * 8;
        if (C < 512) {
          int h = C >> 6, d = C & 63;
          Qb[((size_t)(bh8 + h) * 8 + m) * 8192 + i * 64 + d] = (h16)(val * 0.18033688f);
        } else if (C < 1024) {
          int c2 = C - 512, h = c2 >> 6, d = c2 & 63;
          Kb[((size_t)(bh8 + h) * 1024 + (m * 128 + i)) * 64 + d] = (h16)val;
        } else {
          int c2 = C - 1024, h = c2 >> 6, d = c2 & 63;
          VbT[((size_t)(bh8 + h) * 64 + d) * 1024 + (m * 128 + i)] = (h16)val;
        }
      }
    }
  }
}

// ---------------- attention (round-5 structure, known-pass) ----------------
// grid 512; bh = blk&63 (same bh -> same XCD-L2), z = blk>>6.
// 512 threads = 8 waves -> 16 waves/CU at 2 blocks/CU.
__global__ __launch_bounds__(512, 4) void k_attn(const h16* __restrict__ Qbuf,
                                                 const h16* __restrict__ Kbuf,
                                                 const h16* __restrict__ VbT,
                                                 h16* __restrict__ Ob) {
  __shared__ __align__(16) h16 lds_q[128 * 64];   // Q_m [i][dh], swizzled, 16KB
  __shared__ __align__(16) h16 lds_v[64 * 128];   // V_m [d][j], swizzled, 16KB
  __shared__ __align__(16) h16 lds_p[128][136];   // P^T [i][j], padded, 34.8KB
  int blk = blockIdx.x;
  int bh = blk & 63, z = blk >> 6;
  int b = bh >> 3, h = bh & 7;
  const h16* Qb = Qbuf + (size_t)bh * 65536;              // [m][i][d]
  const h16* Kz = Kbuf + (size_t)bh * 65536 + z * 8192;   // [j][d]
  const h16* Vb = VbT + (size_t)bh * 65536;               // [d][u=m*128+j]
  int tid = threadIdx.x, w = tid >> 6, l = tid & 63, g = l >> 4, t = l & 15;

  int qs_r0 = l >> 3, qs_ch = l & 7;    // Q: 8 rows/KB, chunk of 8 h16
  int vs_r0 = l >> 4, vs_ch = l & 15;   // V: 4 rows/KB, chunk of 8 h16

  // K fragments in registers, loaded ONCE (z-fixed; wave w owns 16 j-rows)
  h16x8 kf[2];
#pragma unroll
  for (int kk = 0; kk < 2; ++kk)
    kf[kk] = *(const h16x8*)&Kz[(w * 16 + t) * 64 + kk * 32 + g * 8];

  f32x4 oa[4];
#pragma unroll
  for (int dt = 0; dt < 4; ++dt) oa[dt] = (f32x4){0.f, 0.f, 0.f, 0.f};

  // prologue: stage Q_0 and V_0
  {
    const h16* Qm = Qb;
#pragma unroll
    for (int s = 0; s < 2; ++s) {
      int r = w * 16 + s * 8 + qs_r0;
      gload16(Qm + r * 64 + ((qs_ch ^ (r & 7)) << 3), &lds_q[(w * 16 + s * 8) * 64]);
    }
#pragma unroll
    for (int s = 0; s < 2; ++s) {
      int r = w * 8 + s * 4 + vs_r0;
      gload16(Vb + (size_t)r * 1024 + ((vs_ch ^ (r & 7)) << 3), &lds_v[(w * 8 + s * 4) * 128]);
    }
  }

  for (int m = 0; m < 8; ++m) {
    __syncthreads();  // staged Q_m/V_m visible (barrier drains DMA vmcnt)

    // T = K_z @ Q_m^T : wave w -> j-rows [w*16,+16) x 128 i-cols
    f32x4 accS[8];
#pragma unroll
    for (int nt = 0; nt < 8; ++nt) accS[nt] = (f32x4){0.f, 0.f, 0.f, 0.f};
#pragma unroll
    for (int kk = 0; kk < 2; ++kk)
#pragma unroll
      for (int nt = 0; nt < 8; ++nt) {
        int rr = nt * 16 + t, c = kk * 4 + g;
        h16x8 bq = *(const h16x8*)&lds_q[rr * 64 + ((c ^ (rr & 7)) << 3)];
        accS[nt] = MFMA16(kf[kk], bq, accS[nt]);
      }

    // softmax over i (cols): in-reg over nt + 16 t-lanes via shfl; no max-sub
    float inv[4];
#pragma unroll
    for (int r = 0; r < 4; ++r) {
      float sum = 0.f;
#pragma unroll
      for (int nt = 0; nt < 8; ++nt) {
        float p = exp2f(accS[nt][r]);
        accS[nt][r] = p;
        sum += p;
      }
#pragma unroll
      for (int msk = 1; msk < 16; msk <<= 1) sum += __shfl_xor(sum, msk);
      inv[r] = 1.f / sum;
    }
    // normalize + cvt + P^T write: lds_p[i = nt*16+t][j = w*16+4g+r]
#pragma unroll
    for (int nt = 0; nt < 8; ++nt) {
      h16x4 pk;
#pragma unroll
      for (int r = 0; r < 4; ++r) pk[r] = (h16)(accS[nt][r] * inv[r]);
      *(h16x4*)&lds_p[nt * 16 + t][w * 16 + 4 * g] = pk;
    }
    __syncthreads();  // lds_p ready; lds_q free

    // overlap: stage Q_{m+1} into lds_q while PV computes
    if (m < 7) {
      const h16* Qm = Qb + (m + 1) * 8192;
#pragma unroll
      for (int s = 0; s < 2; ++s) {
        int r = w * 16 + s * 8 + qs_r0;
        gload16(Qm + r * 64 + ((qs_ch ^ (r & 7)) << 3), &lds_q[(w * 16 + s * 8) * 64]);
      }
    }

    // PV: out[i][d] += sum_j P^T[j][i] * V_m[j][d]; wave w -> i-rows [w*16,+16)
#pragma unroll
    for (int kk = 0; kk < 4; ++kk) {
      h16x8 ap = *(const h16x8*)&lds_p[w * 16 + t][kk * 32 + g * 8];
#pragma unroll
      for (int dt = 0; dt < 4; ++dt) {
        int rr = dt * 16 + t, c = kk * 4 + g;
        h16x8 vf = *(const h16x8*)&lds_v[rr * 128 + ((c ^ (rr & 7)) << 3)];
        oa[dt] = MFMA16(ap, vf, oa[dt]);
      }
    }
    __syncthreads();  // all PV reads of lds_v/lds_p done

    if (m < 7) {
      const h16* Vm = Vb + (m + 1) * 128;
#pragma unroll
      for (int s = 0; s < 2; ++s) {
        int r = w * 8 + s * 4 + vs_r0;
        gload16(Vm + (size_t)r * 1024 + ((vs_ch ^ (r & 7)) << 3), &lds_v[(w * 8 + s * 4) * 128]);
      }
    }
  }

  // store out_z: Ob[b*128 + i][z*512 + h*64 + d]
#pragma unroll
  for (int dt = 0; dt < 4; ++dt)
#pragma unroll
    for (int r = 0; r < 4; ++r) {
      int i = w * 16 + 4 * g + r;
      Ob[(size_t)(b * 128 + i) * 4096 + z * 512 + h * 64 + dt * 16 + t] = (h16)oa[dt][r];
    }
}

// ---------------- final projection GEMM, split-K=4, XCD-chunked ----------
// A = Ob (1024x4096), Bt = woutT (4096 x 4096). Grid 1024 = 4 blocks/CU.
// XCD k gets tileN in [k*4, k*4+4) -> per-XCD woutT slice 4MB, L2-resident.
__global__ __launch_bounds__(256, 4) void k_final_gemm(const h16* __restrict__ A,
                                                       const h16* __restrict__ Bt,
                                                       h16* __restrict__ P) {
  __shared__ __align__(16) h16 As[128 * 64];
  __shared__ __align__(16) h16 Bs[128 * 64];
  int tid = threadIdx.x;
  int lg = (blockIdx.x & 7) * 128 + (blockIdx.x >> 3);
  int tileN = lg >> 5;        // [xcd*4, xcd*4+4)
  int rem = lg & 31;
  int tileM = rem >> 2, ks = rem & 3;
  int w = tid >> 6, l = tid & 63, g = l >> 4, t = l & 15;
  int wr = w >> 1, wc = w & 1;
  int lr = l >> 3, lc = (l & 7) * 8;
  const h16* Abase = A + (size_t)(tileM * 128) * 4096 + ks * 1024;
  const h16* Bbase = Bt + (size_t)(tileN * 128) * 4096 + ks * 1024;
  f32x4 acc[4][4];
#pragma unroll
  for (int i = 0; i < 4; ++i)
#pragma unroll
    for (int j = 0; j < 4; ++j) acc[i][j] = (f32x4){0.f, 0.f, 0.f, 0.f};

  for (int k0 = 0; k0 < 1024; k0 += 64) {
#pragma unroll
    for (int c = 0; c < 4; ++c) {
      int chunk = w * 4 + c, row0 = chunk * 8;
      gload16(Abase + (size_t)(row0 + lr) * 4096 + k0 + lc, &As[chunk * 512]);
      gload16(Bbase + (size_t)(row0 + lr) * 4096 + k0 + lc, &Bs[chunk * 512]);
    }
    __syncthreads();
#pragma unroll
    for (int kk = 0; kk < 64; kk += 32) {
      h16x8 af[4], bfr[4];
#pragma unroll
      for (int mi = 0; mi < 4; ++mi) af[mi] = *(const h16x8*)&As[(wr * 64 + mi * 16 + t) * 64 + kk + g * 8];
#pragma unroll
      for (int ni = 0; ni < 4; ++ni) bfr[ni] = *(const h16x8*)&Bs[(wc * 64 + ni * 16 + t) * 64 + kk + g * 8];
#pragma unroll
      for (int mi = 0; mi < 4; ++mi)
#pragma unroll
        for (int ni = 0; ni < 4; ++ni) acc[mi][ni] = MFMA16(af[mi], bfr[ni], acc[mi][ni]);
    }
    __syncthreads();
  }
  h16* Pk = P + (size_t)ks * 4194304;
#pragma unroll
  for (int mi = 0; mi < 4; ++mi) {
#pragma unroll
    for (int ni = 0; ni < 4; ++ni) {
      int C = tileN * 128 + wc * 64 + ni * 16 + t;
#pragma unroll
      for (int r = 0; r < 4; ++r) {
        int R = tileM * 128 + wr * 64 + mi * 16 + 4 * g + r;
        Pk[(size_t)R * 4096 + C] = (h16)acc[mi][ni][r];
      }
    }
  }
}

// y = p0+p1+p2+p3 + bias; 8 elems/thread, grid 2048
__global__ __launch_bounds__(256) void k_reduce4(const h16* __restrict__ P,
                                                 const float* __restrict__ bias,
                                                 float* __restrict__ Y) {
  int idx = blockIdx.x * 256 + threadIdx.x;
  size_t base = (size_t)idx * 8;
  h16x8 p0 = *(const h16x8*)&P[base];
  h16x8 p1 = *(const h16x8*)&P[base + 4194304];
  h16x8 p2 = *(const h16x8*)&P[base + 8388608];
  h16x8 p3 = *(const h16x8*)&P[base + 12582912];
  int cb = (int)(base & 4095);
  float4 b0 = *(const float4*)&bias[cb];
  float4 b1 = *(const float4*)&bias[cb + 4];
  float4 o0, o1;
  o0.x = (float)p0[0] + (float)p1[0] + (float)p2[0] + (float)p3[0] + b0.x;
  o0.y = (float)p0[1] + (float)p1[1] + (float)p2[1] + (float)p3[1] + b0.y;
  o0.z = (float)p0[2] + (float)p1[2] + (float)p2[2] + (float)p3[2] + b0.z;
  o0.w = (float)p0[3] + (float)p1[3] + (float)p2[3] + (float)p3[3] + b0.w;
  o1.x = (float)p0[4] + (float)p1[4] + (float)p2[4] + (float)p3[4] + b1.x;
  o1.y = (float)p0[5] + (float)p1[5] + (float)p2[5] + (float)p3[5] + b1.y;
  o1.z = (float)p0[6] + (float)p1[6] + (float)p2[6] + (float)p3[6] + b1.z;
  o1.w = (float)p0[7] + (float)p1[7] + (float)p2[7] + (float)p3[7] + b1.w;
  *(float4*)&Y[base] = o0;
  *(float4*)&Y[base + 4] = o1;
}

// ---------------- launch ----------------

extern "C" void kernel_launch(void* const* d_in, const int* in_sizes, int n_in,
                              void* d_out, int out_size, void* d_ws, size_t ws_size,
                              hipStream_t stream) {
  const float* x = (const float*)d_in[0];
  const float* w_q = (const float*)d_in[1];
  const float* w_kv = (const float*)d_in[2];
  const float* w_out = (const float*)d_in[3];
  const float* b_out = (const float*)d_in[4];
  float* y = (float*)d_out;

  char* ws = (char*)d_ws;
  h16* woutT = (h16*)(ws + 0);          // 32 MB  (alive to the end)
  h16* Ob    = (h16*)(ws + 33554432);   //  8 MB  (alive to the end)
  h16* xh    = (h16*)(ws + 41943040);   //  8 MB  (dead after qkv)
  h16* wqkvT = (h16*)(ws + 50331648);   //  1.5MB (dead after qkv)
  h16* Qb    = (h16*)(ws + 51904512);   //  8 MB  (dead after attn)
  h16* Kb    = (h16*)(ws + 60293120);   //  8 MB  (dead after attn)
  h16* VbT   = (h16*)(ws + 68681728);   //  8 MB  (dead after attn)
  h16* Pp    = (h16*)(ws + 41943040);   // 32 MB partials, overlays dead region
  (void)ws_size; (void)in_sizes; (void)n_in; (void)out_size;

  k_convert_x<<<dim3(2048), dim3(256), 0, stream>>>(x, xh);
  k_transpose<<<dim3(8, 8), dim3(64, 4), 0, stream>>>(w_q, wqkvT, 512, 512);
  k_transpose<<<dim3(16, 8), dim3(64, 4), 0, stream>>>(w_kv, wqkvT + 512 * 512, 512, 1024);
  k_transpose<<<dim3(64, 64), dim3(64, 4), 0, stream>>>(w_out, woutT, 4096, 4096);
  k_qkv_gemm<<<dim3(768), dim3(256), 0, stream>>>(xh, wqkvT, Qb, Kb, VbT);
  k_attn<<<dim3(512), dim3(512), 0, stream>>>(Qb, Kb, VbT, Ob);
  k_final_gemm<<<dim3(1024), dim3(256), 0, stream>>>(Ob, woutT, Pp);
  k_reduce4<<<dim3(2048), dim3(256), 0, stream>>>(Pp, b_out, y);
}

// Round 10
// 157.052 us; speedup vs baseline: 1.0793x; 1.0060x over previous
//
#include <hip/hip_runtime.h>

// ---------------------------------------------------------------------------
// Channel_Seq_Big_Attention: B=8,N=128,M=8,D=512,H=8,DH=64, INNER=512
// Softmax is over axis=2 of (b,h,i,j,m,z) == QUERY seq axis i.
// Pipeline (fp16 compute, fp32 accumulate):
//   1. x -> xh (f16); w_q,w_kv -> wqkvT f16 [n][k]; w_out -> woutT [4096][4096]
//   2. QKV GEMM (8192x512)@(512x1536): A,B via global_load_lds with
//      XOR-swizzled global source (bank-conflict-free fragment reads),
//      XCD-chunked grid. Scatter: Qb [bh][m][i][d] (scaled log2e/8),
//      Kb [bh][z][j][d], VbT [bh][d][m*128+j]
//   3. attention (round-5 structure): block=(bh,z), 512 threads, bh=blk&63
//      (XCD-local). 3-barrier m-loop, single lds_v, padded lds_p.
//   4. final GEMM (1024x4096)@(4096x4096), split-K=4, XCD-chunked,
//      swizzled staging, fp16 partials -> k_reduce4 (+bias) -> y (f32)
// Lessons encoded:
//  - r7/r8: do NOT fuse f32->f16 convert into GEMM staging (displaces
//    global_load_lds with a synchronous chain; ~25us latency hit).
//  - r9: linear [row][64] LDS tiles = 16-way bank conflict on b128 fragment
//    reads (12.6M conflict cycles in final GEMM); fix = pre-swizzled global
//    source (chunk ^= row&7) + swizzled read, LDS dest stays linear.
// ---------------------------------------------------------------------------

typedef _Float16 h16;
typedef _Float16 h16x4 __attribute__((ext_vector_type(4)));
typedef _Float16 h16x8 __attribute__((ext_vector_type(8)));
typedef float f32x4 __attribute__((ext_vector_type(4)));

#define MFMA16(a, b, c) __builtin_amdgcn_mfma_f32_16x16x32_f16(a, b, c, 0, 0, 0)

// async global->LDS, 16B per lane; lds dest must be wave-uniform base
__device__ __forceinline__ void gload16(const h16* g, h16* l) {
  __builtin_amdgcn_global_load_lds(
      (const __attribute__((address_space(1))) void*)g,
      (__attribute__((address_space(3))) void*)l, 16, 0, 0);
}

// ---------------- prep kernels ----------------

__global__ __launch_bounds__(256) void k_convert_x(const float* __restrict__ src,
                                                   h16* __restrict__ dst) {
  int idx = blockIdx.x * 256 + threadIdx.x;  // 8 elements per thread
  const float4* s4 = (const float4*)src;
  float4 a = s4[idx * 2];
  float4 b = s4[idx * 2 + 1];
  h16x8 o;
  o[0] = (h16)a.x; o[1] = (h16)a.y; o[2] = (h16)a.z; o[3] = (h16)a.w;
  o[4] = (h16)b.x; o[5] = (h16)b.y; o[6] = (h16)b.z; o[7] = (h16)b.w;
  *(h16x8*)&dst[(size_t)idx * 8] = o;
}

// dst[c][r] = (h16) src[r][c];  R,C multiples of 64. block (64,4)
__global__ __launch_bounds__(256) void k_transpose(const float* __restrict__ src,
                                                   h16* __restrict__ dst, int R, int C) {
  __shared__ h16 tile[64][72];
  int tx = threadIdx.x, ty = threadIdx.y;
  int r0 = blockIdx.y * 64, c0 = blockIdx.x * 64;
#pragma unroll
  for (int s = 0; s < 16; ++s) {
    int r = ty + s * 4;
    tile[r][tx] = (h16)src[(size_t)(r0 + r) * C + c0 + tx];
  }
  __syncthreads();
#pragma unroll
  for (int s = 0; s < 16; ++s) {
    int rr = ty + s * 4;
    dst[(size_t)(c0 + rr) * R + r0 + tx] = tile[tx][rr];
  }
}

// ---------------- QKV projection GEMM (swizzled async staging) ------------
// A = xh (8192x512 f16), Bt = wqkvT (1536 x 512 f16), scatter epilogue.
__global__ __launch_bounds__(256, 3) void k_qkv_gemm(const h16* __restrict__ A,
                                                     const h16* __restrict__ Bt,
                                                     h16* __restrict__ Qb,
                                                     h16* __restrict__ Kb,
                                                     h16* __restrict__ VbT) {
  __shared__ __align__(16) h16 As[128 * 64];
  __shared__ __align__(16) h16 Bs[128 * 64];
  int tid = threadIdx.x;
  // XCD-chunked: XCD k (= blk&7) owns tileM in [k*8,k*8+8) x all 12 tileN.
  int lg = (blockIdx.x & 7) * 96 + (blockIdx.x >> 3);
  int tileM = lg / 12, tileN = lg % 12;
  int w = tid >> 6, l = tid & 63, g = l >> 4, t = l & 15;
  int wr = w >> 1, wc = w & 1;
  int lr = l >> 3, lch = l & 7;  // staging: row-in-chunk, chunk idx
  const h16* Abase = A + (size_t)(tileM * 128) * 512;
  const h16* Bbase = Bt + (size_t)(tileN * 128) * 512;
  f32x4 acc[4][4];
#pragma unroll
  for (int i = 0; i < 4; ++i)
#pragma unroll
    for (int j = 0; j < 4; ++j) acc[i][j] = (f32x4){0.f, 0.f, 0.f, 0.f};

  for (int k0 = 0; k0 < 512; k0 += 64) {
#pragma unroll
    for (int c = 0; c < 4; ++c) {
      int chunk = w * 4 + c, row = chunk * 8 + lr;
      int sc = (lch ^ (row & 7)) * 8;  // pre-swizzled source chunk
      gload16(Abase + (size_t)row * 512 + k0 + sc, &As[chunk * 512]);
      gload16(Bbase + (size_t)row * 512 + k0 + sc, &Bs[chunk * 512]);
    }
    __syncthreads();
#pragma unroll
    for (int kk = 0; kk < 64; kk += 32) {
      h16x8 af[4], bfr[4];
#pragma unroll
      for (int mi = 0; mi < 4; ++mi) {
        int rr = wr * 64 + mi * 16 + t, c = (kk >> 3) + g;
        af[mi] = *(const h16x8*)&As[rr * 64 + ((c ^ (rr & 7)) << 3)];
      }
#pragma unroll
      for (int ni = 0; ni < 4; ++ni) {
        int rr = wc * 64 + ni * 16 + t, c = (kk >> 3) + g;
        bfr[ni] = *(const h16x8*)&Bs[rr * 64 + ((c ^ (rr & 7)) << 3)];
      }
#pragma unroll
      for (int mi = 0; mi < 4; ++mi)
#pragma unroll
        for (int ni = 0; ni < 4; ++ni) acc[mi][ni] = MFMA16(af[mi], bfr[ni], acc[mi][ni]);
    }
    __syncthreads();
  }
  // scatter epilogue: C<512 -> Q (scaled by log2e/8), C<1024 -> K, else -> V^T
#pragma unroll
  for (int mi = 0; mi < 4; ++mi) {
#pragma unroll
    for (int ni = 0; ni < 4; ++ni) {
      int C = tileN * 128 + wc * 64 + ni * 16 + t;
#pragma unroll
      for (int r = 0; r < 4; ++r) {
        int R = tileM * 128 + wr * 64 + mi * 16 + 4 * g + r;
        float val = acc[mi][ni][r];
        int b = R >> 10, rm = R & 1023;
        int i = rm >> 3, m = rm & 7;
        int bh8 = b * 8;
        if (C < 512) {
          int h = C >> 6, d = C & 63;
          Qb[((size_t)(bh8 + h) * 8 + m) * 8192 + i * 64 + d] = (h16)(val * 0.18033688f);
        } else if (C < 1024) {
          int c2 = C - 512, h = c2 >> 6, d = c2 & 63;
          Kb[((size_t)(bh8 + h) * 1024 + (m * 128 + i)) * 64 + d] = (h16)val;
        } else {
          int c2 = C - 1024, h = c2 >> 6, d = c2 & 63;
          VbT[((size_t)(bh8 + h) * 64 + d) * 1024 + (m * 128 + i)] = (h16)val;
        }
      }
    }
  }
}

// ---------------- attention (round-5 structure, known-pass) ----------------
// grid 512; bh = blk&63 (same bh -> same XCD-L2), z = blk>>6.
// 512 threads = 8 waves -> 16 waves/CU at 2 blocks/CU.
__global__ __launch_bounds__(512, 4) void k_attn(const h16* __restrict__ Qbuf,
                                                 const h16* __restrict__ Kbuf,
                                                 const h16* __restrict__ VbT,
                                                 h16* __restrict__ Ob) {
  __shared__ __align__(16) h16 lds_q[128 * 64];   // Q_m [i][dh], swizzled, 16KB
  __shared__ __align__(16) h16 lds_v[64 * 128];   // V_m [d][j], swizzled, 16KB
  __shared__ __align__(16) h16 lds_p[128][136];   // P^T [i][j], padded, 34.8KB
  int blk = blockIdx.x;
  int bh = blk & 63, z = blk >> 6;
  int b = bh >> 3, h = bh & 7;
  const h16* Qb = Qbuf + (size_t)bh * 65536;              // [m][i][d]
  const h16* Kz = Kbuf + (size_t)bh * 65536 + z * 8192;   // [j][d]
  const h16* Vb = VbT + (size_t)bh * 65536;               // [d][u=m*128+j]
  int tid = threadIdx.x, w = tid >> 6, l = tid & 63, g = l >> 4, t = l & 15;

  int qs_r0 = l >> 3, qs_ch = l & 7;    // Q: 8 rows/KB, chunk of 8 h16
  int vs_r0 = l >> 4, vs_ch = l & 15;   // V: 4 rows/KB, chunk of 8 h16

  // K fragments in registers, loaded ONCE (z-fixed; wave w owns 16 j-rows)
  h16x8 kf[2];
#pragma unroll
  for (int kk = 0; kk < 2; ++kk)
    kf[kk] = *(const h16x8*)&Kz[(w * 16 + t) * 64 + kk * 32 + g * 8];

  f32x4 oa[4];
#pragma unroll
  for (int dt = 0; dt < 4; ++dt) oa[dt] = (f32x4){0.f, 0.f, 0.f, 0.f};

  // prologue: stage Q_0 and V_0
  {
    const h16* Qm = Qb;
#pragma unroll
    for (int s = 0; s < 2; ++s) {
      int r = w * 16 + s * 8 + qs_r0;
      gload16(Qm + r * 64 + ((qs_ch ^ (r & 7)) << 3), &lds_q[(w * 16 + s * 8) * 64]);
    }
#pragma unroll
    for (int s = 0; s < 2; ++s) {
      int r = w * 8 + s * 4 + vs_r0;
      gload16(Vb + (size_t)r * 1024 + ((vs_ch ^ (r & 7)) << 3), &lds_v[(w * 8 + s * 4) * 128]);
    }
  }

  for (int m = 0; m < 8; ++m) {
    __syncthreads();  // staged Q_m/V_m visible (barrier drains DMA vmcnt)

    // T = K_z @ Q_m^T : wave w -> j-rows [w*16,+16) x 128 i-cols
    f32x4 accS[8];
#pragma unroll
    for (int nt = 0; nt < 8; ++nt) accS[nt] = (f32x4){0.f, 0.f, 0.f, 0.f};
#pragma unroll
    for (int kk = 0; kk < 2; ++kk)
#pragma unroll
      for (int nt = 0; nt < 8; ++nt) {
        int rr = nt * 16 + t, c = kk * 4 + g;
        h16x8 bq = *(const h16x8*)&lds_q[rr * 64 + ((c ^ (rr & 7)) << 3)];
        accS[nt] = MFMA16(kf[kk], bq, accS[nt]);
      }

    // softmax over i (cols): in-reg over nt + 16 t-lanes via shfl; no max-sub
    float inv[4];
#pragma unroll
    for (int r = 0; r < 4; ++r) {
      float sum = 0.f;
#pragma unroll
      for (int nt = 0; nt < 8; ++nt) {
        float p = exp2f(accS[nt][r]);
        accS[nt][r] = p;
        sum += p;
      }
#pragma unroll
      for (int msk = 1; msk < 16; msk <<= 1) sum += __shfl_xor(sum, msk);
      inv[r] = 1.f / sum;
    }
    // normalize + cvt + P^T write: lds_p[i = nt*16+t][j = w*16+4g+r]
#pragma unroll
    for (int nt = 0; nt < 8; ++nt) {
      h16x4 pk;
#pragma unroll
      for (int r = 0; r < 4; ++r) pk[r] = (h16)(accS[nt][r] * inv[r]);
      *(h16x4*)&lds_p[nt * 16 + t][w * 16 + 4 * g] = pk;
    }
    __syncthreads();  // lds_p ready; lds_q free

    // overlap: stage Q_{m+1} into lds_q while PV computes
    if (m < 7) {
      const h16* Qm = Qb + (m + 1) * 8192;
#pragma unroll
      for (int s = 0; s < 2; ++s) {
        int r = w * 16 + s * 8 + qs_r0;
        gload16(Qm + r * 64 + ((qs_ch ^ (r & 7)) << 3), &lds_q[(w * 16 + s * 8) * 64]);
      }
    }

    // PV: out[i][d] += sum_j P^T[j][i] * V_m[j][d]; wave w -> i-rows [w*16,+16)
#pragma unroll
    for (int kk = 0; kk < 4; ++kk) {
      h16x8 ap = *(const h16x8*)&lds_p[w * 16 + t][kk * 32 + g * 8];
#pragma unroll
      for (int dt = 0; dt < 4; ++dt) {
        int rr = dt * 16 + t, c = kk * 4 + g;
        h16x8 vf = *(const h16x8*)&lds_v[rr * 128 + ((c ^ (rr & 7)) << 3)];
        oa[dt] = MFMA16(ap, vf, oa[dt]);
      }
    }
    __syncthreads();  // all PV reads of lds_v/lds_p done

    if (m < 7) {
      const h16* Vm = Vb + (m + 1) * 128;
#pragma unroll
      for (int s = 0; s < 2; ++s) {
        int r = w * 8 + s * 4 + vs_r0;
        gload16(Vm + (size_t)r * 1024 + ((vs_ch ^ (r & 7)) << 3), &lds_v[(w * 8 + s * 4) * 128]);
      }
    }
  }

  // store out_z: Ob[b*128 + i][z*512 + h*64 + d]
#pragma unroll
  for (int dt = 0; dt < 4; ++dt)
#pragma unroll
    for (int r = 0; r < 4; ++r) {
      int i = w * 16 + 4 * g + r;
      Ob[(size_t)(b * 128 + i) * 4096 + z * 512 + h * 64 + dt * 16 + t] = (h16)oa[dt][r];
    }
}

// ---------------- final projection GEMM, split-K=4, swizzled staging ------
// A = Ob (1024x4096), Bt = woutT (4096 x 4096). Grid 1024 = 4 blocks/CU.
// XCD k gets tileN in [k*4, k*4+4) -> per-XCD woutT slice 4MB, L2-resident.
__global__ __launch_bounds__(256, 4) void k_final_gemm(const h16* __restrict__ A,
                                                       const h16* __restrict__ Bt,
                                                       h16* __restrict__ P) {
  __shared__ __align__(16) h16 As[128 * 64];
  __shared__ __align__(16) h16 Bs[128 * 64];
  int tid = threadIdx.x;
  int lg = (blockIdx.x & 7) * 128 + (blockIdx.x >> 3);
  int tileN = lg >> 5;        // [xcd*4, xcd*4+4)
  int rem = lg & 31;
  int tileM = rem >> 2, ks = rem & 3;
  int w = tid >> 6, l = tid & 63, g = l >> 4, t = l & 15;
  int wr = w >> 1, wc = w & 1;
  int lr = l >> 3, lch = l & 7;
  const h16* Abase = A + (size_t)(tileM * 128) * 4096 + ks * 1024;
  const h16* Bbase = Bt + (size_t)(tileN * 128) * 4096 + ks * 1024;
  f32x4 acc[4][4];
#pragma unroll
  for (int i = 0; i < 4; ++i)
#pragma unroll
    for (int j = 0; j < 4; ++j) acc[i][j] = (f32x4){0.f, 0.f, 0.f, 0.f};

  for (int k0 = 0; k0 < 1024; k0 += 64) {
#pragma unroll
    for (int c = 0; c < 4; ++c) {
      int chunk = w * 4 + c, row = chunk * 8 + lr;
      int sc = (lch ^ (row & 7)) * 8;  // pre-swizzled source chunk
      gload16(Abase + (size_t)row * 4096 + k0 + sc, &As[chunk * 512]);
      gload16(Bbase + (size_t)row * 4096 + k0 + sc, &Bs[chunk * 512]);
    }
    __syncthreads();
#pragma unroll
    for (int kk = 0; kk < 64; kk += 32) {
      h16x8 af[4], bfr[4];
#pragma unroll
      for (int mi = 0; mi < 4; ++mi) {
        int rr = wr * 64 + mi * 16 + t, c = (kk >> 3) + g;
        af[mi] = *(const h16x8*)&As[rr * 64 + ((c ^ (rr & 7)) << 3)];
      }
#pragma unroll
      for (int ni = 0; ni < 4; ++ni) {
        int rr = wc * 64 + ni * 16 + t, c = (kk >> 3) + g;
        bfr[ni] = *(const h16x8*)&Bs[rr * 64 + ((c ^ (rr & 7)) << 3)];
      }
#pragma unroll
      for (int mi = 0; mi < 4; ++mi)
#pragma unroll
        for (int ni = 0; ni < 4; ++ni) acc[mi][ni] = MFMA16(af[mi], bfr[ni], acc[mi][ni]);
    }
    __syncthreads();
  }
  h16* Pk = P + (size_t)ks * 4194304;
#pragma unroll
  for (int mi = 0; mi < 4; ++mi) {
#pragma unroll
    for (int ni = 0; ni < 4; ++ni) {
      int C = tileN * 128 + wc * 64 + ni * 16 + t;
#pragma unroll
      for (int r = 0; r < 4; ++r) {
        int R = tileM * 128 + wr * 64 + mi * 16 + 4 * g + r;
        Pk[(size_t)R * 4096 + C] = (h16)acc[mi][ni][r];
      }
    }
  }
}

// y = p0+p1+p2+p3 + bias; 8 elems/thread, grid 2048
__global__ __launch_bounds__(256) void k_reduce4(const h16* __restrict__ P,
                                                 const float* __restrict__ bias,
                                                 float* __restrict__ Y) {
  int idx = blockIdx.x * 256 + threadIdx.x;
  size_t base = (size_t)idx * 8;
  h16x8 p0 = *(const h16x8*)&P[base];
  h16x8 p1 = *(const h16x8*)&P[base + 4194304];
  h16x8 p2 = *(const h16x8*)&P[base + 8388608];
  h16x8 p3 = *(const h16x8*)&P[base + 12582912];
  int cb = (int)(base & 4095);
  float4 b0 = *(const float4*)&bias[cb];
  float4 b1 = *(const float4*)&bias[cb + 4];
  float4 o0, o1;
  o0.x = (float)p0[0] + (float)p1[0] + (float)p2[0] + (float)p3[0] + b0.x;
  o0.y = (float)p0[1] + (float)p1[1] + (float)p2[1] + (float)p3[1] + b0.y;
  o0.z = (float)p0[2] + (float)p1[2] + (float)p2[2] + (float)p3[2] + b0.z;
  o0.w = (float)p0[3] + (float)p1[3] + (float)p2[3] + (float)p3[3] + b0.w;
  o1.x = (float)p0[4] + (float)p1[4] + (float)p2[4] + (float)p3[4] + b1.x;
  o1.y = (float)p0[5] + (float)p1[5] + (float)p2[5] + (float)p3[5] + b1.y;
  o1.z = (float)p0[6] + (float)p1[6] + (float)p2[6] + (float)p3[6] + b1.z;
  o1.w = (float)p0[7] + (float)p1[7] + (float)p2[7] + (float)p3[7] + b1.w;
  *(float4*)&Y[base] = o0;
  *(float4*)&Y[base + 4] = o1;
}

// ---------------- launch ----------------

extern "C" void kernel_launch(void* const* d_in, const int* in_sizes, int n_in,
                              void* d_out, int out_size, void* d_ws, size_t ws_size,
                              hipStream_t stream) {
  const float* x = (const float*)d_in[0];
  const float* w_q = (const float*)d_in[1];
  const float* w_kv = (const float*)d_in[2];
  const float* w_out = (const float*)d_in[3];
  const float* b_out = (const float*)d_in[4];
  float* y = (float*)d_out;

  char* ws = (char*)d_ws;
  h16* woutT = (h16*)(ws + 0);          // 32 MB  (alive to the end)
  h16* Ob    = (h16*)(ws + 33554432);   //  8 MB  (alive to the end)
  h16* xh    = (h16*)(ws + 41943040);   //  8 MB  (dead after qkv)
  h16* wqkvT = (h16*)(ws + 50331648);   //  1.5MB (dead after qkv)
  h16* Qb    = (h16*)(ws + 51904512);   //  8 MB  (dead after attn)
  h16* Kb    = (h16*)(ws + 60293120);   //  8 MB  (dead after attn)
  h16* VbT   = (h16*)(ws + 68681728);   //  8 MB  (dead after attn)
  h16* Pp    = (h16*)(ws + 41943040);   // 32 MB partials, overlays dead region
  (void)ws_size; (void)in_sizes; (void)n_in; (void)out_size;

  k_convert_x<<<dim3(2048), dim3(256), 0, stream>>>(x, xh);
  k_transpose<<<dim3(8, 8), dim3(64, 4), 0, stream>>>(w_q, wqkvT, 512, 512);
  k_transpose<<<dim3(16, 8), dim3(64, 4), 0, stream>>>(w_kv, wqkvT + 512 * 512, 512, 1024);
  k_transpose<<<dim3(64, 64), dim3(64, 4), 0, stream>>>(w_out, woutT, 4096, 4096);
  k_qkv_gemm<<<dim3(768), dim3(256), 0, stream>>>(xh, wqkvT, Qb, Kb, VbT);
  k_attn<<<dim3(512), dim3(512), 0, stream>>>(Qb, Kb, VbT, Ob);
  k_final_gemm<<<dim3(1024), dim3(256), 0, stream>>>(Ob, woutT, Pp);
  k_reduce4<<<dim3(2048), dim3(256), 0, stream>>>(Pp, b_out, y);
}

// Round 11
// 149.938 us; speedup vs baseline: 1.1305x; 1.0475x over previous
//
#include <hip/hip_runtime.h>

// ---------------------------------------------------------------------------
// Channel_Seq_Big_Attention: B=8,N=128,M=8,D=512,H=8,DH=64, INNER=512
// Softmax is over axis=2 of (b,h,i,j,m,z) == QUERY seq axis i.
// Pipeline (fp16 compute, fp32 accumulate):
//   1. k_prep (single launch): x->xh f16 | w_q,w_kv -> wqkvT [n][k] |
//      w_out -> woutT [4096][4096], all vectorized (float4 / h16x8).
//   2. QKV GEMM: A,B via global_load_lds, pre-swizzled source, XCD-chunked.
//      Scatter: Qb [bh][m][i][d] (scaled log2e/8), Kb [bh][z][j][d],
//      VbT [bh][d][m*128+j]
//   3. attention (round-5 structure, proven): block=(bh,z), 512 threads,
//      bh=blk&63 (XCD-local). 3-barrier m-loop, single lds_v, padded lds_p.
//   4. final GEMM split-K=4, XCD-chunked, swizzled staging, fp16 partials
//      -> k_reduce4 (+bias) -> y (f32)
// Lessons encoded:
//  - r7/r8: do NOT fuse f32->f16 convert into GEMM staging (displaces
//    global_load_lds with a synchronous chain; ~25us latency hit).
//  - r9/r10: linear [row][64] LDS tiles = 16-way conflicts on b128 fragment
//    reads; fix = pre-swizzled global source + swizzled read (12.6M->gone).
//  - r6: 2-barrier attn pipeline failed with stale-tile signature; cause
//    never isolated after exhaustive re-derivation. Do not re-roll blind.
// ---------------------------------------------------------------------------

typedef _Float16 h16;
typedef _Float16 h16x4 __attribute__((ext_vector_type(4)));
typedef _Float16 h16x8 __attribute__((ext_vector_type(8)));
typedef float f32x4 __attribute__((ext_vector_type(4)));

#define MFMA16(a, b, c) __builtin_amdgcn_mfma_f32_16x16x32_f16(a, b, c, 0, 0, 0)

// async global->LDS, 16B per lane; lds dest must be wave-uniform base
__device__ __forceinline__ void gload16(const h16* g, h16* l) {
  __builtin_amdgcn_global_load_lds(
      (const __attribute__((address_space(1))) void*)g,
      (__attribute__((address_space(3))) void*)l, 16, 0, 0);
}

// ---------------- merged prep kernel ----------------
// blocks [0,2048): x->xh convert (8 f32 -> 8 h16 per thread)
// blocks [2048,2112): w_q  T (512x512)   [2112,2240): w_kv T (512x1024)
// blocks [2240,6336): w_out T (4096x4096)
// transpose: dst[c][r] = (h16) src[r][c], 64x64 tile, vectorized both sides.
__global__ __launch_bounds__(256) void k_prep(const float* __restrict__ x,
                                              h16* __restrict__ xh,
                                              const float* __restrict__ w_q,
                                              const float* __restrict__ w_kv,
                                              const float* __restrict__ w_out,
                                              h16* __restrict__ wqkvT,
                                              h16* __restrict__ woutT) {
  __shared__ h16 tile[64][68];
  int blk = blockIdx.x, tid = threadIdx.x;
  if (blk < 2048) {  // convert branch (no barrier used)
    int idx = blk * 256 + tid;
    const float4* s4 = (const float4*)x;
    float4 a = s4[idx * 2];
    float4 b = s4[idx * 2 + 1];
    h16x8 o;
    o[0] = (h16)a.x; o[1] = (h16)a.y; o[2] = (h16)a.z; o[3] = (h16)a.w;
    o[4] = (h16)b.x; o[5] = (h16)b.y; o[6] = (h16)b.z; o[7] = (h16)b.w;
    *(h16x8*)&xh[(size_t)idx * 8] = o;
    return;
  }
  const float* src; h16* dst; int R, C, bx, by;
  if (blk < 2112) {
    int b2 = blk - 2048; src = w_q; dst = wqkvT; R = 512; C = 512;
    bx = b2 & 7; by = b2 >> 3;
  } else if (blk < 2240) {
    int b2 = blk - 2112; src = w_kv; dst = wqkvT + 512 * 512; R = 512; C = 1024;
    bx = b2 & 15; by = b2 >> 4;
  } else {
    int b2 = blk - 2240; src = w_out; dst = woutT; R = 4096; C = 4096;
    bx = b2 & 63; by = b2 >> 6;
  }
  int r0 = by * 64, c0 = bx * 64;
  // load: float4 per thread x4 (rows lr+16s, cols lc..lc+4), cvt, LDS write
  int lr = tid >> 4, lc = (tid & 15) * 4;
#pragma unroll
  for (int s = 0; s < 4; ++s) {
    int r = lr + s * 16;
    float4 v = *(const float4*)&src[(size_t)(r0 + r) * C + c0 + lc];
    h16x4 hq;
    hq[0] = (h16)v.x; hq[1] = (h16)v.y; hq[2] = (h16)v.z; hq[3] = (h16)v.w;
    *(h16x4*)&tile[r][lc] = hq;
  }
  __syncthreads();
  // store: h16x8 per thread x2: dst row c = oc+32s, cols r0+os..+8
  int oc = tid >> 3, os = (tid & 7) * 8;
#pragma unroll
  for (int s = 0; s < 2; ++s) {
    int c = oc + s * 32;
    h16x8 hv;
#pragma unroll
    for (int e = 0; e < 8; ++e) hv[e] = tile[os + e][c];
    *(h16x8*)&dst[(size_t)(c0 + c) * R + r0 + os] = hv;
  }
}

// ---------------- QKV projection GEMM (swizzled async staging) ------------
// A = xh (8192x512 f16), Bt = wqkvT (1536 x 512 f16), scatter epilogue.
__global__ __launch_bounds__(256, 3) void k_qkv_gemm(const h16* __restrict__ A,
                                                     const h16* __restrict__ Bt,
                                                     h16* __restrict__ Qb,
                                                     h16* __restrict__ Kb,
                                                     h16* __restrict__ VbT) {
  __shared__ __align__(16) h16 As[128 * 64];
  __shared__ __align__(16) h16 Bs[128 * 64];
  int tid = threadIdx.x;
  // XCD-chunked: XCD k (= blk&7) owns tileM in [k*8,k*8+8) x all 12 tileN.
  int lg = (blockIdx.x & 7) * 96 + (blockIdx.x >> 3);
  int tileM = lg / 12, tileN = lg % 12;
  int w = tid >> 6, l = tid & 63, g = l >> 4, t = l & 15;
  int wr = w >> 1, wc = w & 1;
  int lr = l >> 3, lch = l & 7;  // staging: row-in-chunk, chunk idx
  const h16* Abase = A + (size_t)(tileM * 128) * 512;
  const h16* Bbase = Bt + (size_t)(tileN * 128) * 512;
  f32x4 acc[4][4];
#pragma unroll
  for (int i = 0; i < 4; ++i)
#pragma unroll
    for (int j = 0; j < 4; ++j) acc[i][j] = (f32x4){0.f, 0.f, 0.f, 0.f};

  for (int k0 = 0; k0 < 512; k0 += 64) {
#pragma unroll
    for (int c = 0; c < 4; ++c) {
      int chunk = w * 4 + c, row = chunk * 8 + lr;
      int sc = (lch ^ (row & 7)) * 8;  // pre-swizzled source chunk
      gload16(Abase + (size_t)row * 512 + k0 + sc, &As[chunk * 512]);
      gload16(Bbase + (size_t)row * 512 + k0 + sc, &Bs[chunk * 512]);
    }
    __syncthreads();
#pragma unroll
    for (int kk = 0; kk < 64; kk += 32) {
      h16x8 af[4], bfr[4];
#pragma unroll
      for (int mi = 0; mi < 4; ++mi) {
        int rr = wr * 64 + mi * 16 + t, c = (kk >> 3) + g;
        af[mi] = *(const h16x8*)&As[rr * 64 + ((c ^ (rr & 7)) << 3)];
      }
#pragma unroll
      for (int ni = 0; ni < 4; ++ni) {
        int rr = wc * 64 + ni * 16 + t, c = (kk >> 3) + g;
        bfr[ni] = *(const h16x8*)&Bs[rr * 64 + ((c ^ (rr & 7)) << 3)];
      }
#pragma unroll
      for (int mi = 0; mi < 4; ++mi)
#pragma unroll
        for (int ni = 0; ni < 4; ++ni) acc[mi][ni] = MFMA16(af[mi], bfr[ni], acc[mi][ni]);
    }
    __syncthreads();
  }
  // scatter epilogue: C<512 -> Q (scaled by log2e/8), C<1024 -> K, else -> V^T
#pragma unroll
  for (int mi = 0; mi < 4; ++mi) {
#pragma unroll
    for (int ni = 0; ni < 4; ++ni) {
      int C = tileN * 128 + wc * 64 + ni * 16 + t;
#pragma unroll
      for (int r = 0; r < 4; ++r) {
        int R = tileM * 128 + wr * 64 + mi * 16 + 4 * g + r;
        float val = acc[mi][ni][r];
        int b = R >> 10, rm = R & 1023;
        int i = rm >> 3, m = rm & 7;
        int bh8 = b * 8;
        if (C < 512) {
          int h = C >> 6, d = C & 63;
          Qb[((size_t)(bh8 + h) * 8 + m) * 8192 + i * 64 + d] = (h16)(val * 0.18033688f);
        } else if (C < 1024) {
          int c2 = C - 512, h = c2 >> 6, d = c2 & 63;
          Kb[((size_t)(bh8 + h) * 1024 + (m * 128 + i)) * 64 + d] = (h16)val;
        } else {
          int c2 = C - 1024, h = c2 >> 6, d = c2 & 63;
          VbT[((size_t)(bh8 + h) * 64 + d) * 1024 + (m * 128 + i)] = (h16)val;
        }
      }
    }
  }
}

// ---------------- attention (round-5 structure, known-pass) ----------------
// grid 512; bh = blk&63 (same bh -> same XCD-L2), z = blk>>6.
// 512 threads = 8 waves -> 16 waves/CU at 2 blocks/CU.
__global__ __launch_bounds__(512, 4) void k_attn(const h16* __restrict__ Qbuf,
                                                 const h16* __restrict__ Kbuf,
                                                 const h16* __restrict__ VbT,
                                                 h16* __restrict__ Ob) {
  __shared__ __align__(16) h16 lds_q[128 * 64];   // Q_m [i][dh], swizzled, 16KB
  __shared__ __align__(16) h16 lds_v[64 * 128];   // V_m [d][j], swizzled, 16KB
  __shared__ __align__(16) h16 lds_p[128][136];   // P^T [i][j], padded, 34.8KB
  int blk = blockIdx.x;
  int bh = blk & 63, z = blk >> 6;
  int b = bh >> 3, h = bh & 7;
  const h16* Qb = Qbuf + (size_t)bh * 65536;              // [m][i][d]
  const h16* Kz = Kbuf + (size_t)bh * 65536 + z * 8192;   // [j][d]
  const h16* Vb = VbT + (size_t)bh * 65536;               // [d][u=m*128+j]
  int tid = threadIdx.x, w = tid >> 6, l = tid & 63, g = l >> 4, t = l & 15;

  int qs_r0 = l >> 3, qs_ch = l & 7;    // Q: 8 rows/KB, chunk of 8 h16
  int vs_r0 = l >> 4, vs_ch = l & 15;   // V: 4 rows/KB, chunk of 8 h16

  // K fragments in registers, loaded ONCE (z-fixed; wave w owns 16 j-rows)
  h16x8 kf[2];
#pragma unroll
  for (int kk = 0; kk < 2; ++kk)
    kf[kk] = *(const h16x8*)&Kz[(w * 16 + t) * 64 + kk * 32 + g * 8];

  f32x4 oa[4];
#pragma unroll
  for (int dt = 0; dt < 4; ++dt) oa[dt] = (f32x4){0.f, 0.f, 0.f, 0.f};

  // prologue: stage Q_0 and V_0
  {
    const h16* Qm = Qb;
#pragma unroll
    for (int s = 0; s < 2; ++s) {
      int r = w * 16 + s * 8 + qs_r0;
      gload16(Qm + r * 64 + ((qs_ch ^ (r & 7)) << 3), &lds_q[(w * 16 + s * 8) * 64]);
    }
#pragma unroll
    for (int s = 0; s < 2; ++s) {
      int r = w * 8 + s * 4 + vs_r0;
      gload16(Vb + (size_t)r * 1024 + ((vs_ch ^ (r & 7)) << 3), &lds_v[(w * 8 + s * 4) * 128]);
    }
  }

  for (int m = 0; m < 8; ++m) {
    __syncthreads();  // staged Q_m/V_m visible (barrier drains DMA vmcnt)

    // T = K_z @ Q_m^T : wave w -> j-rows [w*16,+16) x 128 i-cols
    f32x4 accS[8];
#pragma unroll
    for (int nt = 0; nt < 8; ++nt) accS[nt] = (f32x4){0.f, 0.f, 0.f, 0.f};
#pragma unroll
    for (int kk = 0; kk < 2; ++kk)
#pragma unroll
      for (int nt = 0; nt < 8; ++nt) {
        int rr = nt * 16 + t, c = kk * 4 + g;
        h16x8 bq = *(const h16x8*)&lds_q[rr * 64 + ((c ^ (rr & 7)) << 3)];
        accS[nt] = MFMA16(kf[kk], bq, accS[nt]);
      }

    // softmax over i (cols): in-reg over nt + 16 t-lanes via shfl; no max-sub
    float inv[4];
#pragma unroll
    for (int r = 0; r < 4; ++r) {
      float sum = 0.f;
#pragma unroll
      for (int nt = 0; nt < 8; ++nt) {
        float p = exp2f(accS[nt][r]);
        accS[nt][r] = p;
        sum += p;
      }
#pragma unroll
      for (int msk = 1; msk < 16; msk <<= 1) sum += __shfl_xor(sum, msk);
      inv[r] = 1.f / sum;
    }
    // normalize + cvt + P^T write: lds_p[i = nt*16+t][j = w*16+4g+r]
#pragma unroll
    for (int nt = 0; nt < 8; ++nt) {
      h16x4 pk;
#pragma unroll
      for (int r = 0; r < 4; ++r) pk[r] = (h16)(accS[nt][r] * inv[r]);
      *(h16x4*)&lds_p[nt * 16 + t][w * 16 + 4 * g] = pk;
    }
    __syncthreads();  // lds_p ready; lds_q free

    // overlap: stage Q_{m+1} into lds_q while PV computes
    if (m < 7) {
      const h16* Qm = Qb + (m + 1) * 8192;
#pragma unroll
      for (int s = 0; s < 2; ++s) {
        int r = w * 16 + s * 8 + qs_r0;
        gload16(Qm + r * 64 + ((qs_ch ^ (r & 7)) << 3), &lds_q[(w * 16 + s * 8) * 64]);
      }
    }

    // PV: out[i][d] += sum_j P^T[j][i] * V_m[j][d]; wave w -> i-rows [w*16,+16)
#pragma unroll
    for (int kk = 0; kk < 4; ++kk) {
      h16x8 ap = *(const h16x8*)&lds_p[w * 16 + t][kk * 32 + g * 8];
#pragma unroll
      for (int dt = 0; dt < 4; ++dt) {
        int rr = dt * 16 + t, c = kk * 4 + g;
        h16x8 vf = *(const h16x8*)&lds_v[rr * 128 + ((c ^ (rr & 7)) << 3)];
        oa[dt] = MFMA16(ap, vf, oa[dt]);
      }
    }
    __syncthreads();  // all PV reads of lds_v/lds_p done

    if (m < 7) {
      const h16* Vm = Vb + (m + 1) * 128;
#pragma unroll
      for (int s = 0; s < 2; ++s) {
        int r = w * 8 + s * 4 + vs_r0;
        gload16(Vm + (size_t)r * 1024 + ((vs_ch ^ (r & 7)) << 3), &lds_v[(w * 8 + s * 4) * 128]);
      }
    }
  }

  // store out_z: Ob[b*128 + i][z*512 + h*64 + d]
#pragma unroll
  for (int dt = 0; dt < 4; ++dt)
#pragma unroll
    for (int r = 0; r < 4; ++r) {
      int i = w * 16 + 4 * g + r;
      Ob[(size_t)(b * 128 + i) * 4096 + z * 512 + h * 64 + dt * 16 + t] = (h16)oa[dt][r];
    }
}

// ---------------- final projection GEMM, split-K=4, swizzled staging ------
// A = Ob (1024x4096), Bt = woutT (4096 x 4096). Grid 1024 = 4 blocks/CU.
// XCD k gets tileN in [k*4, k*4+4) -> per-XCD woutT slice 4MB, L2-resident.
__global__ __launch_bounds__(256, 4) void k_final_gemm(const h16* __restrict__ A,
                                                       const h16* __restrict__ Bt,
                                                       h16* __restrict__ P) {
  __shared__ __align__(16) h16 As[128 * 64];
  __shared__ __align__(16) h16 Bs[128 * 64];
  int tid = threadIdx.x;
  int lg = (blockIdx.x & 7) * 128 + (blockIdx.x >> 3);
  int tileN = lg >> 5;        // [xcd*4, xcd*4+4)
  int rem = lg & 31;
  int tileM = rem >> 2, ks = rem & 3;
  int w = tid >> 6, l = tid & 63, g = l >> 4, t = l & 15;
  int wr = w >> 1, wc = w & 1;
  int lr = l >> 3, lch = l & 7;
  const h16* Abase = A + (size_t)(tileM * 128) * 4096 + ks * 1024;
  const h16* Bbase = Bt + (size_t)(tileN * 128) * 4096 + ks * 1024;
  f32x4 acc[4][4];
#pragma unroll
  for (int i = 0; i < 4; ++i)
#pragma unroll
    for (int j = 0; j < 4; ++j) acc[i][j] = (f32x4){0.f, 0.f, 0.f, 0.f};

  for (int k0 = 0; k0 < 1024; k0 += 64) {
#pragma unroll
    for (int c = 0; c < 4; ++c) {
      int chunk = w * 4 + c, row = chunk * 8 + lr;
      int sc = (lch ^ (row & 7)) * 8;  // pre-swizzled source chunk
      gload16(Abase + (size_t)row * 4096 + k0 + sc, &As[chunk * 512]);
      gload16(Bbase + (size_t)row * 4096 + k0 + sc, &Bs[chunk * 512]);
    }
    __syncthreads();
#pragma unroll
    for (int kk = 0; kk < 64; kk += 32) {
      h16x8 af[4], bfr[4];
#pragma unroll
      for (int mi = 0; mi < 4; ++mi) {
        int rr = wr * 64 + mi * 16 + t, c = (kk >> 3) + g;
        af[mi] = *(const h16x8*)&As[rr * 64 + ((c ^ (rr & 7)) << 3)];
      }
#pragma unroll
      for (int ni = 0; ni < 4; ++ni) {
        int rr = wc * 64 + ni * 16 + t, c = (kk >> 3) + g;
        bfr[ni] = *(const h16x8*)&Bs[rr * 64 + ((c ^ (rr & 7)) << 3)];
      }
#pragma unroll
      for (int mi = 0; mi < 4; ++mi)
#pragma unroll
        for (int ni = 0; ni < 4; ++ni) acc[mi][ni] = MFMA16(af[mi], bfr[ni], acc[mi][ni]);
    }
    __syncthreads();
  }
  h16* Pk = P + (size_t)ks * 4194304;
#pragma unroll
  for (int mi = 0; mi < 4; ++mi) {
#pragma unroll
    for (int ni = 0; ni < 4; ++ni) {
      int C = tileN * 128 + wc * 64 + ni * 16 + t;
#pragma unroll
      for (int r = 0; r < 4; ++r) {
        int R = tileM * 128 + wr * 64 + mi * 16 + 4 * g + r;
        Pk[(size_t)R * 4096 + C] = (h16)acc[mi][ni][r];
      }
    }
  }
}

// y = p0+p1+p2+p3 + bias; 8 elems/thread, grid 2048
__global__ __launch_bounds__(256) void k_reduce4(const h16* __restrict__ P,
                                                 const float* __restrict__ bias,
                                                 float* __restrict__ Y) {
  int idx = blockIdx.x * 256 + threadIdx.x;
  size_t base = (size_t)idx * 8;
  h16x8 p0 = *(const h16x8*)&P[base];
  h16x8 p1 = *(const h16x8*)&P[base + 4194304];
  h16x8 p2 = *(const h16x8*)&P[base + 8388608];
  h16x8 p3 = *(const h16x8*)&P[base + 12582912];
  int cb = (int)(base & 4095);
  float4 b0 = *(const float4*)&bias[cb];
  float4 b1 = *(const float4*)&bias[cb + 4];
  float4 o0, o1;
  o0.x = (float)p0[0] + (float)p1[0] + (float)p2[0] + (float)p3[0] + b0.x;
  o0.y = (float)p0[1] + (float)p1[1] + (float)p2[1] + (float)p3[1] + b0.y;
  o0.z = (float)p0[2] + (float)p1[2] + (float)p2[2] + (float)p3[2] + b0.z;
  o0.w = (float)p0[3] + (float)p1[3] + (float)p2[3] + (float)p3[3] + b0.w;
  o1.x = (float)p0[4] + (float)p1[4] + (float)p2[4] + (float)p3[4] + b1.x;
  o1.y = (float)p0[5] + (float)p1[5] + (float)p2[5] + (float)p3[5] + b1.y;
  o1.z = (float)p0[6] + (float)p1[6] + (float)p2[6] + (float)p3[6] + b1.z;
  o1.w = (float)p0[7] + (float)p1[7] + (float)p2[7] + (float)p3[7] + b1.w;
  *(float4*)&Y[base] = o0;
  *(float4*)&Y[base + 4] = o1;
}

// ---------------- launch ----------------

extern "C" void kernel_launch(void* const* d_in, const int* in_sizes, int n_in,
                              void* d_out, int out_size, void* d_ws, size_t ws_size,
                              hipStream_t stream) {
  const float* x = (const float*)d_in[0];
  const float* w_q = (const float*)d_in[1];
  const float* w_kv = (const float*)d_in[2];
  const float* w_out = (const float*)d_in[3];
  const float* b_out = (const float*)d_in[4];
  float* y = (float*)d_out;

  char* ws = (char*)d_ws;
  h16* woutT = (h16*)(ws + 0);          // 32 MB  (alive to the end)
  h16* Ob    = (h16*)(ws + 33554432);   //  8 MB  (alive to the end)
  h16* xh    = (h16*)(ws + 41943040);   //  8 MB  (dead after qkv)
  h16* wqkvT = (h16*)(ws + 50331648);   //  1.5MB (dead after qkv)
  h16* Qb    = (h16*)(ws + 51904512);   //  8 MB  (dead after attn)
  h16* Kb    = (h16*)(ws + 60293120);   //  8 MB  (dead after attn)
  h16* VbT   = (h16*)(ws + 68681728);   //  8 MB  (dead after attn)
  h16* Pp    = (h16*)(ws + 41943040);   // 32 MB partials, overlays dead region
  (void)ws_size; (void)in_sizes; (void)n_in; (void)out_size;

  k_prep<<<dim3(6336), dim3(256), 0, stream>>>(x, xh, w_q, w_kv, w_out, wqkvT, woutT);
  k_qkv_gemm<<<dim3(768), dim3(256), 0, stream>>>(xh, wqkvT, Qb, Kb, VbT);
  k_attn<<<dim3(512), dim3(512), 0, stream>>>(Qb, Kb, VbT, Ob);
  k_final_gemm<<<dim3(1024), dim3(256), 0, stream>>>(Ob, woutT, Pp);
  k_reduce4<<<dim3(2048), dim3(256), 0, stream>>>(Pp, b_out, y);
}

// Round 12
// 145.970 us; speedup vs baseline: 1.1612x; 1.0272x over previous
//
#include <hip/hip_runtime.h>

// ---------------------------------------------------------------------------
// Channel_Seq_Big_Attention: B=8,N=128,M=8,D=512,H=8,DH=64, INNER=512
// Softmax is over axis=2 of (b,h,i,j,m,z) == QUERY seq axis i.
// Pipeline (fp16 compute, fp32 accumulate):
//   1. k_prep_small: x->xh f16 | w_q,w_kv -> wqkvT [n][k] (vectorized).
//   2. k_qkv_gemm (merged launch): blk<768 = QKV GEMM (async swizzled
//      staging, XCD-chunked); blk>=768 = w_out transpose tiles (woutT,
//      needed only by final GEMM) -- co-resident at 32KB LDS/block, fills
//      the BW the latency-bound GEMM blocks leave idle.
//      Scatter: Qb [bh][m][i][d] (scaled log2e/8), Kb [bh][z][j][d],
//      VbT [bh][d][m*128+j]
//   3. attention (round-5 structure, proven): block=(bh,z), 512 threads,
//      bh=blk&63 (XCD-local). 3-barrier m-loop, single lds_v, padded lds_p.
//   4. final GEMM split-K=4, XCD-chunked, swizzled staging, fp16 partials
//      -> k_reduce4 (+bias) -> y (f32)
// Lessons encoded:
//  - r7/r8: do NOT fuse f32->f16 convert into GEMM staging (sync chain).
//  - r9/r10: linear [row][64] LDS tiles = 16-way b128 conflicts; fix =
//    pre-swizzled global source + swizzled read.
//  - r6 (diagnosed r11): the failed 2-barrier attn used an 8-byte-granule
//    lds_p swizzle -> ds_read_b128 at 8-mod-16 addresses (misaligned).
//    Any future lds_p swizzle must use 16B granules.
//  - r11: static LDS is per-kernel; co-residency merges only work when the
//    host kernel's declared LDS is small (qkv 32KB yes, attn 67.5KB no).
// ---------------------------------------------------------------------------

typedef _Float16 h16;
typedef _Float16 h16x4 __attribute__((ext_vector_type(4)));
typedef _Float16 h16x8 __attribute__((ext_vector_type(8)));
typedef float f32x4 __attribute__((ext_vector_type(4)));

#define MFMA16(a, b, c) __builtin_amdgcn_mfma_f32_16x16x32_f16(a, b, c, 0, 0, 0)

// async global->LDS, 16B per lane; lds dest must be wave-uniform base
__device__ __forceinline__ void gload16(const h16* g, h16* l) {
  __builtin_amdgcn_global_load_lds(
      (const __attribute__((address_space(1))) void*)g,
      (__attribute__((address_space(3))) void*)l, 16, 0, 0);
}

// ---------------- prep kernel (x convert + wqkv transpose) ----------------
// blocks [0,2048): x->xh convert; [2048,2112): w_q T; [2112,2240): w_kv T
__global__ __launch_bounds__(256) void k_prep_small(const float* __restrict__ x,
                                                    h16* __restrict__ xh,
                                                    const float* __restrict__ w_q,
                                                    const float* __restrict__ w_kv,
                                                    h16* __restrict__ wqkvT) {
  __shared__ h16 tile[64][68];
  int blk = blockIdx.x, tid = threadIdx.x;
  if (blk < 2048) {  // convert branch (no barrier used)
    int idx = blk * 256 + tid;
    const float4* s4 = (const float4*)x;
    float4 a = s4[idx * 2];
    float4 b = s4[idx * 2 + 1];
    h16x8 o;
    o[0] = (h16)a.x; o[1] = (h16)a.y; o[2] = (h16)a.z; o[3] = (h16)a.w;
    o[4] = (h16)b.x; o[5] = (h16)b.y; o[6] = (h16)b.z; o[7] = (h16)b.w;
    *(h16x8*)&xh[(size_t)idx * 8] = o;
    return;
  }
  const float* src; h16* dst; int R, C, bx, by;
  if (blk < 2112) {
    int b2 = blk - 2048; src = w_q; dst = wqkvT; R = 512; C = 512;
    bx = b2 & 7; by = b2 >> 3;
  } else {
    int b2 = blk - 2112; src = w_kv; dst = wqkvT + 512 * 512; R = 512; C = 1024;
    bx = b2 & 15; by = b2 >> 4;
  }
  int r0 = by * 64, c0 = bx * 64;
  int lr = tid >> 4, lc = (tid & 15) * 4;
#pragma unroll
  for (int s = 0; s < 4; ++s) {
    int r = lr + s * 16;
    float4 v = *(const float4*)&src[(size_t)(r0 + r) * C + c0 + lc];
    h16x4 hq;
    hq[0] = (h16)v.x; hq[1] = (h16)v.y; hq[2] = (h16)v.z; hq[3] = (h16)v.w;
    *(h16x4*)&tile[r][lc] = hq;
  }
  __syncthreads();
  int oc = tid >> 3, os = (tid & 7) * 8;
#pragma unroll
  for (int s = 0; s < 2; ++s) {
    int c = oc + s * 32;
    h16x8 hv;
#pragma unroll
    for (int e = 0; e < 8; ++e) hv[e] = tile[os + e][c];
    *(h16x8*)&dst[(size_t)(c0 + c) * R + r0 + os] = hv;
  }
}

// ------- QKV GEMM + co-resident w_out transpose (merged launch) -----------
// blk < 768: GEMM A = xh (8192x512 f16), Bt = wqkvT, scatter epilogue.
// blk >= 768: 64x64 transpose tile of w_out (4096x4096 f32) -> woutT f16.
__global__ __launch_bounds__(256, 3) void k_qkv_gemm(const h16* __restrict__ A,
                                                     const h16* __restrict__ Bt,
                                                     const float* __restrict__ w_out,
                                                     h16* __restrict__ Qb,
                                                     h16* __restrict__ Kb,
                                                     h16* __restrict__ VbT,
                                                     h16* __restrict__ woutT) {
  __shared__ __align__(16) h16 As[128 * 64];
  __shared__ __align__(16) h16 Bs[128 * 64];
  int tid = threadIdx.x;

  if (blockIdx.x >= 768) {  // ---- w_out transpose tile (reuses As as LDS) ----
    h16(*tile)[68] = (h16(*)[68])As;
    int b2 = blockIdx.x - 768;
    int bx = b2 & 63, by = b2 >> 6;
    int r0 = by * 64, c0 = bx * 64;
    int lr = tid >> 4, lc = (tid & 15) * 4;
#pragma unroll
    for (int s = 0; s < 4; ++s) {
      int r = lr + s * 16;
      float4 v = *(const float4*)&w_out[(size_t)(r0 + r) * 4096 + c0 + lc];
      h16x4 hq;
      hq[0] = (h16)v.x; hq[1] = (h16)v.y; hq[2] = (h16)v.z; hq[3] = (h16)v.w;
      *(h16x4*)&tile[r][lc] = hq;
    }
    __syncthreads();
    int oc = tid >> 3, os = (tid & 7) * 8;
#pragma unroll
    for (int s = 0; s < 2; ++s) {
      int c = oc + s * 32;
      h16x8 hv;
#pragma unroll
      for (int e = 0; e < 8; ++e) hv[e] = tile[os + e][c];
      *(h16x8*)&woutT[(size_t)(c0 + c) * 4096 + r0 + os] = hv;
    }
    return;
  }

  // ---- GEMM branch: XCD-chunked (XCD k owns tileM [k*8,k*8+8) x 12 tileN) --
  int lg = (blockIdx.x & 7) * 96 + (blockIdx.x >> 3);
  int tileM = lg / 12, tileN = lg % 12;
  int w = tid >> 6, l = tid & 63, g = l >> 4, t = l & 15;
  int wr = w >> 1, wc = w & 1;
  int lr = l >> 3, lch = l & 7;  // staging: row-in-chunk, chunk idx
  const h16* Abase = A + (size_t)(tileM * 128) * 512;
  const h16* Bbase = Bt + (size_t)(tileN * 128) * 512;
  f32x4 acc[4][4];
#pragma unroll
  for (int i = 0; i < 4; ++i)
#pragma unroll
    for (int j = 0; j < 4; ++j) acc[i][j] = (f32x4){0.f, 0.f, 0.f, 0.f};

  for (int k0 = 0; k0 < 512; k0 += 64) {
#pragma unroll
    for (int c = 0; c < 4; ++c) {
      int chunk = w * 4 + c, row = chunk * 8 + lr;
      int sc = (lch ^ (row & 7)) * 8;  // pre-swizzled source chunk
      gload16(Abase + (size_t)row * 512 + k0 + sc, &As[chunk * 512]);
      gload16(Bbase + (size_t)row * 512 + k0 + sc, &Bs[chunk * 512]);
    }
    __syncthreads();
#pragma unroll
    for (int kk = 0; kk < 64; kk += 32) {
      h16x8 af[4], bfr[4];
#pragma unroll
      for (int mi = 0; mi < 4; ++mi) {
        int rr = wr * 64 + mi * 16 + t, c = (kk >> 3) + g;
        af[mi] = *(const h16x8*)&As[rr * 64 + ((c ^ (rr & 7)) << 3)];
      }
#pragma unroll
      for (int ni = 0; ni < 4; ++ni) {
        int rr = wc * 64 + ni * 16 + t, c = (kk >> 3) + g;
        bfr[ni] = *(const h16x8*)&Bs[rr * 64 + ((c ^ (rr & 7)) << 3)];
      }
#pragma unroll
      for (int mi = 0; mi < 4; ++mi)
#pragma unroll
        for (int ni = 0; ni < 4; ++ni) acc[mi][ni] = MFMA16(af[mi], bfr[ni], acc[mi][ni]);
    }
    __syncthreads();
  }
  // scatter epilogue: C<512 -> Q (scaled by log2e/8), C<1024 -> K, else -> V^T
#pragma unroll
  for (int mi = 0; mi < 4; ++mi) {
#pragma unroll
    for (int ni = 0; ni < 4; ++ni) {
      int C = tileN * 128 + wc * 64 + ni * 16 + t;
#pragma unroll
      for (int r = 0; r < 4; ++r) {
        int R = tileM * 128 + wr * 64 + mi * 16 + 4 * g + r;
        float val = acc[mi][ni][r];
        int b = R >> 10, rm = R & 1023;
        int i = rm >> 3, m = rm & 7;
        int bh8 = b * 8;
        if (C < 512) {
          int h = C >> 6, d = C & 63;
          Qb[((size_t)(bh8 + h) * 8 + m) * 8192 + i * 64 + d] = (h16)(val * 0.18033688f);
        } else if (C < 1024) {
          int c2 = C - 512, h = c2 >> 6, d = c2 & 63;
          Kb[((size_t)(bh8 + h) * 1024 + (m * 128 + i)) * 64 + d] = (h16)val;
        } else {
          int c2 = C - 1024, h = c2 >> 6, d = c2 & 63;
          VbT[((size_t)(bh8 + h) * 64 + d) * 1024 + (m * 128 + i)] = (h16)val;
        }
      }
    }
  }
}

// ---------------- attention (round-5 structure, known-pass) ----------------
// grid 512; bh = blk&63 (same bh -> same XCD-L2), z = blk>>6.
// 512 threads = 8 waves -> 16 waves/CU at 2 blocks/CU.
__global__ __launch_bounds__(512, 4) void k_attn(const h16* __restrict__ Qbuf,
                                                 const h16* __restrict__ Kbuf,
                                                 const h16* __restrict__ VbT,
                                                 h16* __restrict__ Ob) {
  __shared__ __align__(16) h16 lds_q[128 * 64];   // Q_m [i][dh], swizzled, 16KB
  __shared__ __align__(16) h16 lds_v[64 * 128];   // V_m [d][j], swizzled, 16KB
  __shared__ __align__(16) h16 lds_p[128][136];   // P^T [i][j], padded, 34.8KB
  int blk = blockIdx.x;
  int bh = blk & 63, z = blk >> 6;
  int b = bh >> 3, h = bh & 7;
  const h16* Qb = Qbuf + (size_t)bh * 65536;              // [m][i][d]
  const h16* Kz = Kbuf + (size_t)bh * 65536 + z * 8192;   // [j][d]
  const h16* Vb = VbT + (size_t)bh * 65536;               // [d][u=m*128+j]
  int tid = threadIdx.x, w = tid >> 6, l = tid & 63, g = l >> 4, t = l & 15;

  int qs_r0 = l >> 3, qs_ch = l & 7;    // Q: 8 rows/KB, chunk of 8 h16
  int vs_r0 = l >> 4, vs_ch = l & 15;   // V: 4 rows/KB, chunk of 8 h16

  // K fragments in registers, loaded ONCE (z-fixed; wave w owns 16 j-rows)
  h16x8 kf[2];
#pragma unroll
  for (int kk = 0; kk < 2; ++kk)
    kf[kk] = *(const h16x8*)&Kz[(w * 16 + t) * 64 + kk * 32 + g * 8];

  f32x4 oa[4];
#pragma unroll
  for (int dt = 0; dt < 4; ++dt) oa[dt] = (f32x4){0.f, 0.f, 0.f, 0.f};

  // prologue: stage Q_0 and V_0
  {
    const h16* Qm = Qb;
#pragma unroll
    for (int s = 0; s < 2; ++s) {
      int r = w * 16 + s * 8 + qs_r0;
      gload16(Qm + r * 64 + ((qs_ch ^ (r & 7)) << 3), &lds_q[(w * 16 + s * 8) * 64]);
    }
#pragma unroll
    for (int s = 0; s < 2; ++s) {
      int r = w * 8 + s * 4 + vs_r0;
      gload16(Vb + (size_t)r * 1024 + ((vs_ch ^ (r & 7)) << 3), &lds_v[(w * 8 + s * 4) * 128]);
    }
  }

  for (int m = 0; m < 8; ++m) {
    __syncthreads();  // staged Q_m/V_m visible (barrier drains DMA vmcnt)

    // T = K_z @ Q_m^T : wave w -> j-rows [w*16,+16) x 128 i-cols
    f32x4 accS[8];
#pragma unroll
    for (int nt = 0; nt < 8; ++nt) accS[nt] = (f32x4){0.f, 0.f, 0.f, 0.f};
#pragma unroll
    for (int kk = 0; kk < 2; ++kk)
#pragma unroll
      for (int nt = 0; nt < 8; ++nt) {
        int rr = nt * 16 + t, c = kk * 4 + g;
        h16x8 bq = *(const h16x8*)&lds_q[rr * 64 + ((c ^ (rr & 7)) << 3)];
        accS[nt] = MFMA16(kf[kk], bq, accS[nt]);
      }

    // softmax over i (cols): in-reg over nt + 16 t-lanes via shfl; no max-sub
    float inv[4];
#pragma unroll
    for (int r = 0; r < 4; ++r) {
      float sum = 0.f;
#pragma unroll
      for (int nt = 0; nt < 8; ++nt) {
        float p = exp2f(accS[nt][r]);
        accS[nt][r] = p;
        sum += p;
      }
#pragma unroll
      for (int msk = 1; msk < 16; msk <<= 1) sum += __shfl_xor(sum, msk);
      inv[r] = 1.f / sum;
    }
    // normalize + cvt + P^T write: lds_p[i = nt*16+t][j = w*16+4g+r]
#pragma unroll
    for (int nt = 0; nt < 8; ++nt) {
      h16x4 pk;
#pragma unroll
      for (int r = 0; r < 4; ++r) pk[r] = (h16)(accS[nt][r] * inv[r]);
      *(h16x4*)&lds_p[nt * 16 + t][w * 16 + 4 * g] = pk;
    }
    __syncthreads();  // lds_p ready; lds_q free

    // overlap: stage Q_{m+1} into lds_q while PV computes
    if (m < 7) {
      const h16* Qm = Qb + (m + 1) * 8192;
#pragma unroll
      for (int s = 0; s < 2; ++s) {
        int r = w * 16 + s * 8 + qs_r0;
        gload16(Qm + r * 64 + ((qs_ch ^ (r & 7)) << 3), &lds_q[(w * 16 + s * 8) * 64]);
      }
    }

    // PV: out[i][d] += sum_j P^T[j][i] * V_m[j][d]; wave w -> i-rows [w*16,+16)
#pragma unroll
    for (int kk = 0; kk < 4; ++kk) {
      h16x8 ap = *(const h16x8*)&lds_p[w * 16 + t][kk * 32 + g * 8];
#pragma unroll
      for (int dt = 0; dt < 4; ++dt) {
        int rr = dt * 16 + t, c = kk * 4 + g;
        h16x8 vf = *(const h16x8*)&lds_v[rr * 128 + ((c ^ (rr & 7)) << 3)];
        oa[dt] = MFMA16(ap, vf, oa[dt]);
      }
    }
    __syncthreads();  // all PV reads of lds_v/lds_p done

    if (m < 7) {
      const h16* Vm = Vb + (m + 1) * 128;
#pragma unroll
      for (int s = 0; s < 2; ++s) {
        int r = w * 8 + s * 4 + vs_r0;
        gload16(Vm + (size_t)r * 1024 + ((vs_ch ^ (r & 7)) << 3), &lds_v[(w * 8 + s * 4) * 128]);
      }
    }
  }

  // store out_z: Ob[b*128 + i][z*512 + h*64 + d]
#pragma unroll
  for (int dt = 0; dt < 4; ++dt)
#pragma unroll
    for (int r = 0; r < 4; ++r) {
      int i = w * 16 + 4 * g + r;
      Ob[(size_t)(b * 128 + i) * 4096 + z * 512 + h * 64 + dt * 16 + t] = (h16)oa[dt][r];
    }
}

// ---------------- final projection GEMM, split-K=4, swizzled staging ------
// A = Ob (1024x4096), Bt = woutT (4096 x 4096). Grid 1024 = 4 blocks/CU.
// XCD k gets tileN in [k*4, k*4+4) -> per-XCD woutT slice 4MB, L2-resident.
__global__ __launch_bounds__(256, 4) void k_final_gemm(const h16* __restrict__ A,
                                                       const h16* __restrict__ Bt,
                                                       h16* __restrict__ P) {
  __shared__ __align__(16) h16 As[128 * 64];
  __shared__ __align__(16) h16 Bs[128 * 64];
  int tid = threadIdx.x;
  int lg = (blockIdx.x & 7) * 128 + (blockIdx.x >> 3);
  int tileN = lg >> 5;        // [xcd*4, xcd*4+4)
  int rem = lg & 31;
  int tileM = rem >> 2, ks = rem & 3;
  int w = tid >> 6, l = tid & 63, g = l >> 4, t = l & 15;
  int wr = w >> 1, wc = w & 1;
  int lr = l >> 3, lch = l & 7;
  const h16* Abase = A + (size_t)(tileM * 128) * 4096 + ks * 1024;
  const h16* Bbase = Bt + (size_t)(tileN * 128) * 4096 + ks * 1024;
  f32x4 acc[4][4];
#pragma unroll
  for (int i = 0; i < 4; ++i)
#pragma unroll
    for (int j = 0; j < 4; ++j) acc[i][j] = (f32x4){0.f, 0.f, 0.f, 0.f};

  for (int k0 = 0; k0 < 1024; k0 += 64) {
#pragma unroll
    for (int c = 0; c < 4; ++c) {
      int chunk = w * 4 + c, row = chunk * 8 + lr;
      int sc = (lch ^ (row & 7)) * 8;  // pre-swizzled source chunk
      gload16(Abase + (size_t)row * 4096 + k0 + sc, &As[chunk * 512]);
      gload16(Bbase + (size_t)row * 4096 + k0 + sc, &Bs[chunk * 512]);
    }
    __syncthreads();
#pragma unroll
    for (int kk = 0; kk < 64; kk += 32) {
      h16x8 af[4], bfr[4];
#pragma unroll
      for (int mi = 0; mi < 4; ++mi) {
        int rr = wr * 64 + mi * 16 + t, c = (kk >> 3) + g;
        af[mi] = *(const h16x8*)&As[rr * 64 + ((c ^ (rr & 7)) << 3)];
      }
#pragma unroll
      for (int ni = 0; ni < 4; ++ni) {
        int rr = wc * 64 + ni * 16 + t, c = (kk >> 3) + g;
        bfr[ni] = *(const h16x8*)&Bs[rr * 64 + ((c ^ (rr & 7)) << 3)];
      }
#pragma unroll
      for (int mi = 0; mi < 4; ++mi)
#pragma unroll
        for (int ni = 0; ni < 4; ++ni) acc[mi][ni] = MFMA16(af[mi], bfr[ni], acc[mi][ni]);
    }
    __syncthreads();
  }
  h16* Pk = P + (size_t)ks * 4194304;
#pragma unroll
  for (int mi = 0; mi < 4; ++mi) {
#pragma unroll
    for (int ni = 0; ni < 4; ++ni) {
      int C = tileN * 128 + wc * 64 + ni * 16 + t;
#pragma unroll
      for (int r = 0; r < 4; ++r) {
        int R = tileM * 128 + wr * 64 + mi * 16 + 4 * g + r;
        Pk[(size_t)R * 4096 + C] = (h16)acc[mi][ni][r];
      }
    }
  }
}

// y = p0+p1+p2+p3 + bias; 8 elems/thread, grid 2048
__global__ __launch_bounds__(256) void k_reduce4(const h16* __restrict__ P,
                                                 const float* __restrict__ bias,
                                                 float* __restrict__ Y) {
  int idx = blockIdx.x * 256 + threadIdx.x;
  size_t base = (size_t)idx * 8;
  h16x8 p0 = *(const h16x8*)&P[base];
  h16x8 p1 = *(const h16x8*)&P[base + 4194304];
  h16x8 p2 = *(const h16x8*)&P[base + 8388608];
  h16x8 p3 = *(const h16x8*)&P[base + 12582912];
  int cb = (int)(base & 4095);
  float4 b0 = *(const float4*)&bias[cb];
  float4 b1 = *(const float4*)&bias[cb + 4];
  float4 o0, o1;
  o0.x = (float)p0[0] + (float)p1[0] + (float)p2[0] + (float)p3[0] + b0.x;
  o0.y = (float)p0[1] + (float)p1[1] + (float)p2[1] + (float)p3[1] + b0.y;
  o0.z = (float)p0[2] + (float)p1[2] + (float)p2[2] + (float)p3[2] + b0.z;
  o0.w = (float)p0[3] + (float)p1[3] + (float)p2[3] + (float)p3[3] + b0.w;
  o1.x = (float)p0[4] + (float)p1[4] + (float)p2[4] + (float)p3[4] + b1.x;
  o1.y = (float)p0[5] + (float)p1[5] + (float)p2[5] + (float)p3[5] + b1.y;
  o1.z = (float)p0[6] + (float)p1[6] + (float)p2[6] + (float)p3[6] + b1.z;
  o1.w = (float)p0[7] + (float)p1[7] + (float)p2[7] + (float)p3[7] + b1.w;
  *(float4*)&Y[base] = o0;
  *(float4*)&Y[base + 4] = o1;
}

// ---------------- launch ----------------

extern "C" void kernel_launch(void* const* d_in, const int* in_sizes, int n_in,
                              void* d_out, int out_size, void* d_ws, size_t ws_size,
                              hipStream_t stream) {
  const float* x = (const float*)d_in[0];
  const float* w_q = (const float*)d_in[1];
  const float* w_kv = (const float*)d_in[2];
  const float* w_out = (const float*)d_in[3];
  const float* b_out = (const float*)d_in[4];
  float* y = (float*)d_out;

  char* ws = (char*)d_ws;
  h16* woutT = (h16*)(ws + 0);          // 32 MB  (alive to the end)
  h16* Ob    = (h16*)(ws + 33554432);   //  8 MB  (alive to the end)
  h16* xh    = (h16*)(ws + 41943040);   //  8 MB  (dead after qkv)
  h16* wqkvT = (h16*)(ws + 50331648);   //  1.5MB (dead after qkv)
  h16* Qb    = (h16*)(ws + 51904512);   //  8 MB  (dead after attn)
  h16* Kb    = (h16*)(ws + 60293120);   //  8 MB  (dead after attn)
  h16* VbT   = (h16*)(ws + 68681728);   //  8 MB  (dead after attn)
  h16* Pp    = (h16*)(ws + 41943040);   // 32 MB partials, overlays dead region
  (void)ws_size; (void)in_sizes; (void)n_in; (void)out_size;

  k_prep_small<<<dim3(2240), dim3(256), 0, stream>>>(x, xh, w_q, w_kv, wqkvT);
  k_qkv_gemm<<<dim3(4864), dim3(256), 0, stream>>>(xh, wqkvT, w_out, Qb, Kb, VbT, woutT);
  k_attn<<<dim3(512), dim3(512), 0, stream>>>(Qb, Kb, VbT, Ob);
  k_final_gemm<<<dim3(1024), dim3(256), 0, stream>>>(Ob, woutT, Pp);
  k_reduce4<<<dim3(2048), dim3(256), 0, stream>>>(Pp, b_out, y);
}